// Round 8
// baseline (494.278 us; speedup 1.0000x reference)
//
#include <hip/hip_runtime.h>
#include <math.h>

// Problem constants
#define B 64
#define D 2048
#define H 4096
#define NSEED 50000
#define KTOP 50
#define NCAND 64            // rescored candidates per row
#define CEMIT 20            // candidates emitted per chunk (coverage: P(chunk holds >20 of top-64) ~ 2e-20)
#define NCHUNKS 64          // topk chunks per row
#define CHUNK_SZ 782        // ceil(50000/64)

// ws layout (float offsets)
#define WS_LOGITS   0                         // 64*50000 = 3,200,000 (also MLP partials: max 8*64*4096 = 2.1M)
#define WS_H        3200000                   // 64*4096  = 262,144
#define WS_Q2       (WS_H + B*H)              // 64*2048  = 131,072
#define WS_PART     (WS_Q2 + B*D)             // 1,048,576 (cand/rvals/tidx live here)
#define WS_CVAL     (WS_PART + 1048576)       // 64*64*20 = 81,920 (region sized 262,144)
#define WS_CIDX     (WS_CVAL + 262144)        // ints
#define WS_CM       (WS_CIDX + 262144)        // 4096
#define WS_CS       (WS_CM + 4096)            // 4096
#define WS_RM       (WS_CS + 4096)            // 64
#define WS_RS       (WS_RM + 64)              // 64
#define WS_Q2HL     (WS_RS + 64)              // q2h+q2l: 2*131072 ushorts = 131,072 floats
// sub-allocations inside the PART region:
#define WSP_CAND    200000                    // 64*64 ints
#define WSP_RVAL    220000                    // 64*64 floats
#define WSP_TIDX    240000                    // 64*50 ints

typedef short s16x8 __attribute__((ext_vector_type(8)));
typedef float f32x4 __attribute__((ext_vector_type(4)));

// ---------------------------------------------------------------------------
// bf16 split helpers: x ~= hi + lo, both RNE bf16.
// ---------------------------------------------------------------------------
__device__ __forceinline__ unsigned short bf16_rne(float x)
{
    unsigned int b = __float_as_uint(x);
    b += 0x7FFFu + ((b >> 16) & 1u);
    return (unsigned short)(b >> 16);
}
__device__ __forceinline__ float bf16_tof(unsigned short h)
{
    return __uint_as_float(((unsigned int)h) << 16);
}

// ---------------------------------------------------------------------------
// MLP GEMM, pipelined fp32 (kept fp32 deliberately — q2 accuracy gates the
// topk-index ordering; bf16-split here would exceed the ~6e-6 min rank-gap).
// C_partial[kc][64][N] = A[64][Kc] @ W[Kc][N]
// ---------------------------------------------------------------------------
__global__ __launch_bounds__(256) void gemm64p_kernel(
    const float* __restrict__ A, const float* __restrict__ W,
    float* __restrict__ part, int K, int N, int kcK, int nBlocks)
{
    __shared__ float As[2][32][68];   // [buf][k][m]
    __shared__ float Bs[2][32][68];   // [buf][k][n]

    const int tid = threadIdx.x;
    const int nb = blockIdx.x % nBlocks;
    const int kc = blockIdx.x / nBlocks;
    const int kbeg = kc * kcK;

    const int tidm = tid >> 4;          // 0..15
    const int tidn = tid & 15;          // 0..15
    const int m0 = tidm * 4;
    const int n0 = tidn * 4;

    const int ar0 = tid >> 3, ac0 = tid & 7;    // + second A float4 at row ar0+32
    const int wr0 = tid >> 4, wc0 = tid & 15;   // + second B float4 at k-row wr0+16

    const float* Aptr0 = A + (size_t)ar0 * K + kbeg + ac0 * 4;
    const float* Aptr1 = A + (size_t)(ar0 + 32) * K + kbeg + ac0 * 4;
    const float* Wptr0 = W + (size_t)(kbeg + wr0) * N + nb * 64 + wc0 * 4;
    const float* Wptr1 = W + (size_t)(kbeg + wr0 + 16) * N + nb * 64 + wc0 * 4;

    float acc[4][4];
#pragma unroll
    for (int i = 0; i < 4; ++i)
#pragma unroll
        for (int j = 0; j < 4; ++j) acc[i][j] = 0.f;

    float4 pa0 = *(const float4*)(Aptr0);
    float4 pa1 = *(const float4*)(Aptr1);
    float4 pb0 = *(const float4*)(Wptr0);
    float4 pb1 = *(const float4*)(Wptr1);

    const int nsteps = kcK / 32;
    for (int s = 0; s < nsteps; ++s) {
        const int buf = s & 1;
        As[buf][ac0 * 4 + 0][ar0] = pa0.x;
        As[buf][ac0 * 4 + 1][ar0] = pa0.y;
        As[buf][ac0 * 4 + 2][ar0] = pa0.z;
        As[buf][ac0 * 4 + 3][ar0] = pa0.w;
        As[buf][ac0 * 4 + 0][ar0 + 32] = pa1.x;
        As[buf][ac0 * 4 + 1][ar0 + 32] = pa1.y;
        As[buf][ac0 * 4 + 2][ar0 + 32] = pa1.z;
        As[buf][ac0 * 4 + 3][ar0 + 32] = pa1.w;
        *(float4*)&Bs[buf][wr0][wc0 * 4] = pb0;
        *(float4*)&Bs[buf][wr0 + 16][wc0 * 4] = pb1;
        if (s + 1 < nsteps) {
            const int ko = 32 * (s + 1);
            pa0 = *(const float4*)(Aptr0 + ko);
            pa1 = *(const float4*)(Aptr1 + ko);
            pb0 = *(const float4*)(Wptr0 + (size_t)ko * N);
            pb1 = *(const float4*)(Wptr1 + (size_t)ko * N);
        }
        __syncthreads();
#pragma unroll
        for (int kk = 0; kk < 32; ++kk) {
            float4 a = *(const float4*)&As[buf][kk][m0];
            float4 b = *(const float4*)&Bs[buf][kk][n0];
            float av[4] = {a.x, a.y, a.z, a.w};
            float bv[4] = {b.x, b.y, b.z, b.w};
#pragma unroll
            for (int i = 0; i < 4; ++i)
#pragma unroll
                for (int j = 0; j < 4; ++j)
                    acc[i][j] += av[i] * bv[j];
        }
    }

#pragma unroll
    for (int i = 0; i < 4; ++i) {
        float4 v;
        v.x = acc[i][0]; v.y = acc[i][1]; v.z = acc[i][2]; v.w = acc[i][3];
        *(float4*)(part + (size_t)(kc * B + m0 + i) * N + nb * 64 + n0) = v;
    }
}

// Reduce K-chunk partials + bias (+ optional exact GELU).
// When uh/ul are non-null (layer 2), also emits the bf16 hi/lo split of out.
__global__ void mlp_reduce_kernel(const float* __restrict__ part,
                                  const float* __restrict__ bias,
                                  float* __restrict__ out, int N, int nchunks, int gelu,
                                  unsigned short* __restrict__ uh,
                                  unsigned short* __restrict__ ul)
{
    int e = blockIdx.x * 256 + threadIdx.x;   // over B*N
    int b = e / N, j = e - b * N;
    float s = bias[j];
    for (int c = 0; c < nchunks; ++c)
        s += part[(size_t)(c * B + b) * N + j];
    if (gelu)
        s = 0.5f * s * (1.0f + erff(s * 0.70710678118654752f));
    out[e] = s;
    if (uh) {
        unsigned short h = bf16_rne(s);
        uh[e] = h;
        ul[e] = bf16_rne(s - bf16_tof(h));
    }
}

// int64-layout hedge for vritti_types (values 0..4 -> high words all zero)
__device__ __forceinline__ bool types_is_i64(const int* t)
{
    int acc = 0;
#pragma unroll
    for (int j = 0; j < 16; ++j) acc |= t[2 * j + 1];
    return acc == 0;
}

// ---------------------------------------------------------------------------
// sims via split-bf16 MFMA — BARRIER-FREE, LDS-FREE.
// logits = (q2 @ seed^T)*gate + vbias[type]
// grid = 782 (64-col tiles), 256 threads = 4 waves; wave w owns 16 seed cols.
// A fragments (q2 hi/lo, 512 KB, L2-resident) are loaded DIRECTLY from
// global per phase — no LDS staging, so no __syncthreads, so the compiler's
// vmcnt(0)-before-barrier drain (m97 stall) cannot collapse the B pipeline.
// B (seed rows, HBM, read-once) prefetched 2 phases (~1200 cyc) ahead into
// static register sets. A duplication costs ~1.6 GB of L2 (~46 us of L2 BW),
// concurrent with the 64 us HBM stream.
// ---------------------------------------------------------------------------
__global__ __launch_bounds__(256) void sims_mfma_kernel(
    const unsigned short* __restrict__ q2h, const unsigned short* __restrict__ q2l,
    const float* __restrict__ seed,
    const float* __restrict__ karma, const int* __restrict__ types,
    const float* __restrict__ vbias, float* __restrict__ logits)
{
    const int tid = threadIdx.x;
    const int n0 = blockIdx.x * 64;
    const int lane = tid & 63;
    const int wv  = tid >> 6;       // 0..3: n-tile of this wave
    const int l15 = lane & 15;
    const int lg  = lane >> 4;      // k-group 0..3

    const int nrow = n0 + wv * 16 + l15;            // seed row this lane owns
    const bool nvalid = nrow < NSEED;
    const float* brow = seed + (size_t)nrow * D + 8 * lg;
    const unsigned short* qh = q2h + (size_t)l15 * D + 8 * lg;
    const unsigned short* ql = q2l + (size_t)l15 * D + 8 * lg;

    f32x4 acc[4];
#pragma unroll
    for (int t = 0; t < 4; ++t) acc[t] = (f32x4){0.f, 0.f, 0.f, 0.f};

    // -------- B pipeline registers (2 sets, static names, depth 2) --------
    float4 b00, b01, b02, b03;      // even phases: k +[0,4,32,36]
    float4 b10, b11, b12, b13;      // odd phases
    b00 = b01 = b02 = b03 = make_float4(0.f, 0.f, 0.f, 0.f);
    b10 = b11 = b12 = b13 = make_float4(0.f, 0.f, 0.f, 0.f);
    if (nvalid) {
        b00 = *(const float4*)(brow);      b01 = *(const float4*)(brow + 4);
        b02 = *(const float4*)(brow + 32); b03 = *(const float4*)(brow + 36);
        b10 = *(const float4*)(brow + 64); b11 = *(const float4*)(brow + 68);
        b12 = *(const float4*)(brow + 96); b13 = *(const float4*)(brow + 100);
    }

#define SIMS_CONV(F0, F1, BH, BL)                                          \
    {                                                                      \
        float xs[8] = {F0.x, F0.y, F0.z, F0.w, F1.x, F1.y, F1.z, F1.w};    \
        _Pragma("unroll")                                                  \
        for (int j = 0; j < 8; ++j) {                                      \
            unsigned short hu = bf16_rne(xs[j]);                           \
            BH[j] = (short)hu;                                             \
            BL[j] = (short)bf16_rne(xs[j] - bf16_tof(hu));                 \
        }                                                                  \
    }

    // One half-step (32 K): direct-from-L2 A fragments + 12 MFMA
#define SIMS_HALF(KOFF, BH, BL)                                            \
    {                                                                      \
        s16x8 ah[4], al[4];                                                \
        _Pragma("unroll")                                                  \
        for (int t = 0; t < 4; ++t) {                                      \
            ah[t] = *(const s16x8*)(qh + (size_t)t * 16 * D + (KOFF));     \
            al[t] = *(const s16x8*)(ql + (size_t)t * 16 * D + (KOFF));     \
        }                                                                  \
        _Pragma("unroll")                                                  \
        for (int t = 0; t < 4; ++t) {                                      \
            acc[t] = __builtin_amdgcn_mfma_f32_16x16x32_bf16(ah[t], BH, acc[t], 0, 0, 0); \
            acc[t] = __builtin_amdgcn_mfma_f32_16x16x32_bf16(al[t], BH, acc[t], 0, 0, 0); \
            acc[t] = __builtin_amdgcn_mfma_f32_16x16x32_bf16(ah[t], BL, acc[t], 0, 0, 0); \
        }                                                                  \
    }

    for (int u = 0; u < 16; ++u) {
        // ================= even phase: kb = 128u, set 0 =================
        {
            const int kb = 128 * u;
            float4 na = make_float4(0.f, 0.f, 0.f, 0.f), nb = na, nc = na, nd = na;
            if (u < 15 && nvalid) {              // prefetch phase 2u+2
                na = *(const float4*)(brow + kb + 128);
                nb = *(const float4*)(brow + kb + 132);
                nc = *(const float4*)(brow + kb + 160);
                nd = *(const float4*)(brow + kb + 164);
            }
            s16x8 bh, bl;
            SIMS_CONV(b00, b01, bh, bl);
            SIMS_HALF(kb, bh, bl);
            SIMS_CONV(b02, b03, bh, bl);
            SIMS_HALF(kb + 32, bh, bl);
            b00 = na; b01 = nb; b02 = nc; b03 = nd;
        }
        // ================= odd phase: kb = 128u + 64, set 1 =================
        {
            const int kb = 128 * u + 64;
            float4 na = make_float4(0.f, 0.f, 0.f, 0.f), nb = na, nc = na, nd = na;
            if (u < 15 && nvalid) {              // prefetch phase 2u+3
                na = *(const float4*)(brow + kb + 128);
                nb = *(const float4*)(brow + kb + 132);
                nc = *(const float4*)(brow + kb + 160);
                nd = *(const float4*)(brow + kb + 164);
            }
            s16x8 bh, bl;
            SIMS_CONV(b10, b11, bh, bl);
            SIMS_HALF(kb, bh, bl);
            SIMS_CONV(b12, b13, bh, bl);
            SIMS_HALF(kb + 32, bh, bl);
            b10 = na; b11 = nb; b12 = nc; b13 = nd;
        }
    }
#undef SIMS_CONV
#undef SIMS_HALF

    // epilogue: gate + vritti bias. D layout: col=lane&15, row=4*lg+reg.
    if (nvalid) {
        const bool i64 = types_is_i64(types);
        float ka = karma[nrow];
        float gate = 1.0f / (1.0f + expf(-(ka + 0.3f) * 10.0f));
        int ty = i64 ? types[2 * nrow] : types[nrow];
        float bias = vbias[ty];
#pragma unroll
        for (int t = 0; t < 4; ++t) {
#pragma unroll
            for (int r = 0; r < 4; ++r) {
                int m = t * 16 + lg * 4 + r;
                logits[(size_t)m * NSEED + nrow] = acc[t][r] * gate + bias;
            }
        }
    }
}

// ---------------------------------------------------------------------------
// Per-(row,chunk): online softmax partial (m,s) + chunk top-CEMIT.
// grid = 64 rows * 64 chunks, 64 threads (1 wave).
// ---------------------------------------------------------------------------
__global__ __launch_bounds__(64) void chunk_topk_kernel(
    const float* __restrict__ logits,
    float* __restrict__ chunk_m, float* __restrict__ chunk_s,
    float* __restrict__ cand_val, int* __restrict__ cand_idx)
{
    const int bid = blockIdx.x;
    const int row = bid >> 6, chunk = bid & 63;
    const int start = chunk * CHUNK_SZ;
    const int end = min(start + CHUNK_SZ, NSEED);
    const int lane = threadIdx.x;
    const float* Lrow = logits + (size_t)row * NSEED;

    float v[13];
#pragma unroll
    for (int j = 0; j < 13; ++j) {
        int e = start + lane + j * 64;
        v[j] = (e < end) ? Lrow[e] : -INFINITY;
    }

    // online (m, s) partial: s = sum exp(2*(l - m))
    float m = v[0];
#pragma unroll
    for (int j = 1; j < 13; ++j) m = fmaxf(m, v[j]);
    float s = 0.f;
#pragma unroll
    for (int j = 0; j < 13; ++j) s += expf(2.f * (v[j] - m));
#pragma unroll
    for (int d = 1; d < 64; d <<= 1) {
        float mo = __shfl_xor(m, d);
        float so = __shfl_xor(s, d);
        float nm = fmaxf(m, mo);
        s = s * expf(2.f * (m - nm)) + so * expf(2.f * (mo - nm));
        m = nm;
    }
    if (lane == 0) { chunk_m[bid] = m; chunk_s[bid] = s; }

    // chunk top-CEMIT via wave-argmax iterations (lower index wins ties)
    for (int it = 0; it < CEMIT; ++it) {
        float bv = v[0]; int bj = 0;
#pragma unroll
        for (int j = 1; j < 13; ++j)
            if (v[j] > bv) { bv = v[j]; bj = j; }
        int bi = start + lane + bj * 64;
#pragma unroll
        for (int d = 1; d < 64; d <<= 1) {
            float ov = __shfl_xor(bv, d);
            int oi = __shfl_xor(bi, d);
            if (ov > bv || (ov == bv && oi < bi)) { bv = ov; bi = oi; }
        }
        if (lane == 0) {
            cand_val[bid * CEMIT + it] = bv;
            cand_idx[bid * CEMIT + it] = bi;
        }
#pragma unroll
        for (int j = 0; j < 13; ++j)
            if (start + lane + j * 64 == bi) v[j] = -INFINITY;
    }
}

// ---------------------------------------------------------------------------
// Per-row merge: 64 (m,s) partials -> (M, 1/S); 1280 candidates -> top-NCAND
// candidate indices (by MFMA logit; candidate set, not final order).
// ---------------------------------------------------------------------------
__global__ __launch_bounds__(256) void merge_topk_kernel(
    const float* __restrict__ chunk_m, const float* __restrict__ chunk_s,
    const float* __restrict__ cand_val, const int* __restrict__ cand_idx,
    float* __restrict__ row_M, float* __restrict__ row_rS,
    int* __restrict__ cand2)
{
    const int row = blockIdx.x;
    const int tid = threadIdx.x;
    const int lane = tid & 63, wave = tid >> 6;
    __shared__ float rv[4];
    __shared__ int ri[4];

    if (wave == 0) {
        float m = chunk_m[row * 64 + lane];
        float s = chunk_s[row * 64 + lane];
#pragma unroll
        for (int d = 1; d < 64; d <<= 1) {
            float mo = __shfl_xor(m, d);
            float so = __shfl_xor(s, d);
            float nm = fmaxf(m, mo);
            s = s * expf(2.f * (m - nm)) + so * expf(2.f * (mo - nm));
            m = nm;
        }
        if (lane == 0) { row_M[row] = m; row_rS[row] = 1.0f / s; }
    }

    float v[5]; int ix[5];
#pragma unroll
    for (int j = 0; j < 5; ++j) {
        int e = tid + j * 256;                      // 1280 = NCHUNKS*CEMIT
        v[j] = cand_val[row * (NCHUNKS * CEMIT) + e];
        ix[j] = cand_idx[row * (NCHUNKS * CEMIT) + e];
    }

    for (int it = 0; it < NCAND; ++it) {
        float bv = v[0]; int bi = ix[0];
#pragma unroll
        for (int j = 1; j < 5; ++j)
            if (v[j] > bv || (v[j] == bv && ix[j] < bi)) { bv = v[j]; bi = ix[j]; }
#pragma unroll
        for (int d = 1; d < 64; d <<= 1) {
            float ov = __shfl_xor(bv, d);
            int oi = __shfl_xor(bi, d);
            if (ov > bv || (ov == bv && oi < bi)) { bv = ov; bi = oi; }
        }
        if (lane == 0) { rv[wave] = bv; ri[wave] = bi; }
        __syncthreads();
        float wv = rv[0]; int wi = ri[0];
#pragma unroll
        for (int w = 1; w < 4; ++w)
            if (rv[w] > wv || (rv[w] == wv && ri[w] < wi)) { wv = rv[w]; wi = ri[w]; }
        __syncthreads();
        if (tid == 0) cand2[row * NCAND + it] = wi;
#pragma unroll
        for (int j = 0; j < 5; ++j)
            if (ix[j] == wi) v[j] = -INFINITY;
    }
}

// ---------------------------------------------------------------------------
// Exact rescore of candidates: fp64 dot(q2[row], seed[idx]) + fp32 gate/bias.
// grid = (NCAND/4, 64 rows), 256 threads = 4 waves (one candidate per wave).
// ---------------------------------------------------------------------------
__global__ __launch_bounds__(256) void rescore_kernel(
    const float* __restrict__ q2, const float* __restrict__ seed,
    const float* __restrict__ karma, const int* __restrict__ types,
    const float* __restrict__ vbias, const int* __restrict__ cand2,
    float* __restrict__ rvals)
{
    const int row = blockIdx.y;
    const int wv = threadIdx.x >> 6, lane = threadIdx.x & 63;
    const int ci = blockIdx.x * 4 + wv;             // 0..NCAND-1
    const int idx = cand2[row * NCAND + ci];
    const float* qrow = q2 + (size_t)row * D;
    const float* srow = seed + (size_t)idx * D;

    double s = 0.0;
#pragma unroll
    for (int i = 0; i < 8; ++i) {
        float4 a = *(const float4*)(qrow + lane * 4 + i * 256);
        float4 b = *(const float4*)(srow + lane * 4 + i * 256);
        s += (double)a.x * (double)b.x + (double)a.y * (double)b.y
           + (double)a.z * (double)b.z + (double)a.w * (double)b.w;
    }
#pragma unroll
    for (int d = 1; d < 64; d <<= 1) s += __shfl_xor(s, d);

    if (lane == 0) {
        float ka = karma[idx];
        float gate = 1.0f / (1.0f + expf(-(ka + 0.3f) * 10.0f));
        bool i64 = types_is_i64(types);
        int ty = i64 ? types[2 * idx] : types[idx];
        rvals[row * NCAND + ci] = (float)s * gate + vbias[ty];
    }
}

// ---------------------------------------------------------------------------
// Final per-row top-50 (sorted desc, lower index on ties) from NCAND rescored.
// grid = 64, 64 threads (1 wave, one candidate per lane).
// ---------------------------------------------------------------------------
__global__ __launch_bounds__(64) void final50_kernel(
    const float* __restrict__ rvals, const int* __restrict__ cand2,
    float* __restrict__ out_idx_f, int* __restrict__ topk_idx)
{
    const int row = blockIdx.x;
    const int lane = threadIdx.x;

    float v = rvals[row * NCAND + lane];
    int ix = cand2[row * NCAND + lane];

    for (int it = 0; it < KTOP; ++it) {
        float bv = v; int bi = ix;
#pragma unroll
        for (int d = 1; d < 64; d <<= 1) {
            float ov = __shfl_xor(bv, d);
            int oi = __shfl_xor(bi, d);
            if (ov > bv || (ov == bv && oi < bi)) { bv = ov; bi = oi; }
        }
        if (lane == 0) {
            out_idx_f[row * KTOP + it] = (float)bi;
            topk_idx[row * KTOP + it] = bi;
        }
        if (ix == bi) v = -INFINITY;
    }
}

// attention weights: w = exp(2*(l - M)) / S
__global__ void weights_kernel(const float* __restrict__ logits,
                               const float* __restrict__ row_M,
                               const float* __restrict__ row_rS,
                               float* __restrict__ attn)
{
    const int row = blockIdx.y;
    const int f = blockIdx.x * 256 + threadIdx.x;
    if (f >= NSEED / 4) return;
    const float M = row_M[row], rS = row_rS[row];
    float4 l = ((const float4*)(logits + (size_t)row * NSEED))[f];
    float4 w;
    w.x = expf(2.f * (l.x - M)) * rS;
    w.y = expf(2.f * (l.y - M)) * rS;
    w.z = expf(2.f * (l.z - M)) * rS;
    w.w = expf(2.f * (l.w - M)) * rS;
    ((float4*)(attn + (size_t)row * NSEED))[f] = w;
}

// chitta gather: 2048 floats per (row,k)
__global__ void gather_kernel(const float* __restrict__ seed,
                              const int* __restrict__ topk_idx,
                              float* __restrict__ chitta)
{
    const int k = blockIdx.x, row = blockIdx.y;
    const int idx = topk_idx[row * KTOP + k];
    const float4* src = (const float4*)(seed + (size_t)idx * D);
    float4* dst = (float4*)(chitta + (size_t)(row * KTOP + k) * D);
#pragma unroll
    for (int j = 0; j < 2; ++j)
        dst[threadIdx.x + j * 256] = src[threadIdx.x + j * 256];
}

extern "C" void kernel_launch(void* const* d_in, const int* in_sizes, int n_in,
                              void* d_out, int out_size, void* d_ws, size_t ws_size,
                              hipStream_t stream)
{
    const float* query = (const float*)d_in[0];
    const int*   types = (const int*)d_in[1];
    const float* seed  = (const float*)d_in[2];
    const float* karma = (const float*)d_in[3];
    const float* vbias = (const float*)d_in[4];
    const float* W1    = (const float*)d_in[5];
    const float* b1    = (const float*)d_in[6];
    const float* W2    = (const float*)d_in[7];
    const float* b2    = (const float*)d_in[8];

    float* ws = (float*)d_ws;
    float* logits = ws + WS_LOGITS;   // also MLP partial buffer (freed before sims)
    float* h      = ws + WS_H;
    float* q2     = ws + WS_Q2;
    float* part   = ws + WS_PART;
    float* cval   = ws + WS_CVAL;
    int*   cidx   = (int*)(ws + WS_CIDX);
    float* cm     = ws + WS_CM;
    float* cs     = ws + WS_CS;
    float* rM     = ws + WS_RM;
    float* rS     = ws + WS_RS;

    // q2 bf16 hi/lo live in their own region (written by fused mlp_reduce L2)
    unsigned short* q2h = (unsigned short*)(ws + WS_Q2HL);   // 64*2048 ushorts
    unsigned short* q2l = q2h + (size_t)B * D;

    // sub-allocations inside PART:
    int*   cand2 = (int*)(part + WSP_CAND);                   // 64*64
    float* rvals = part + WSP_RVAL;                           // 64*64
    int*   tidx  = (int*)(part + WSP_TIDX);                   // 64*50

    float* outv   = (float*)d_out;
    float* chitta = outv;                                   // [64][50][2048]
    float* attn   = outv + (size_t)B * KTOP * D;            // [64][50000]
    float* oidxf  = attn + (size_t)B * NSEED;               // [64][50] as float

    // MLP layer 1: 64 n-blocks x 8 k-chunks (kcK=256) -> 512 blocks, 2/CU
    gemm64p_kernel<<<64 * 8, 256, 0, stream>>>(query, W1, logits, D, H, 256, 64);
    mlp_reduce_kernel<<<(B * H) / 256, 256, 0, stream>>>(logits, b1, h, H, 8, 1, nullptr, nullptr);
    // MLP layer 2: 32 n-blocks x 8 k-chunks (kcK=512) -> 256 blocks; fused q2 split
    gemm64p_kernel<<<32 * 8, 256, 0, stream>>>(h, W2, logits, H, D, 512, 32);
    mlp_reduce_kernel<<<(B * D) / 256, 256, 0, stream>>>(logits, b2, q2, D, 8, 0, q2h, q2l);
    // similarity + gate + bias -> logits (barrier-free, LDS-free MFMA)
    sims_mfma_kernel<<<(NSEED + 63) / 64, 256, 0, stream>>>(q2h, q2l, seed, karma, types, vbias, logits);
    // per-chunk stats + top-20 candidates
    chunk_topk_kernel<<<B * NCHUNKS, 64, 0, stream>>>(logits, cm, cs, cval, cidx);
    // per-row merge -> (M, 1/S) + top-NCAND candidate set
    merge_topk_kernel<<<B, 256, 0, stream>>>(cm, cs, cval, cidx, rM, rS, cand2);
    // exact fp64 rescore of candidates
    rescore_kernel<<<dim3(NCAND / 4, B), 256, 0, stream>>>(q2, seed, karma, types, vbias, cand2, rvals);
    // final sorted top-50 indices
    final50_kernel<<<B, 64, 0, stream>>>(rvals, cand2, oidxf, tidx);
    // full attention weights
    weights_kernel<<<dim3((NSEED / 4 + 255) / 256, B), 256, 0, stream>>>(logits, rM, rS, attn);
    // retrieved embeddings
    gather_kernel<<<dim3(KTOP, B), 256, 0, stream>>>(seed, tidx, chitta);
}

// Round 9
// 347.349 us; speedup vs baseline: 1.4230x; 1.4230x over previous
//
#include <hip/hip_runtime.h>
#include <math.h>

// Problem constants
#define B 64
#define D 2048
#define H 4096
#define NSEED 50000
#define KTOP 50
#define NCAND 64            // rescored candidates per row
#define CEMIT 20            // candidates emitted per chunk (P(chunk holds >20 of top-64) ~ 2e-20)
#define NCHUNKS 64          // topk chunks per row
#define CHUNK_SZ 782        // ceil(50000/64)

// ws layout (float offsets)
#define WS_LOGITS   0                         // 64*50000 = 3,200,000 (also MLP partials: max 16*64*2048 = 2.1M)
#define WS_H        3200000                   // 64*4096  = 262,144
#define WS_Q2       (WS_H + B*H)              // 64*2048  = 131,072
#define WS_PART     (WS_Q2 + B*D)             // 1,048,576 (cand/rvals/tidx live here)
#define WS_CVAL     (WS_PART + 1048576)       // 64*64*20 = 81,920 (region sized 262,144)
#define WS_CIDX     (WS_CVAL + 262144)        // ints
#define WS_CM       (WS_CIDX + 262144)        // 4096
#define WS_CS       (WS_CM + 4096)            // 4096
#define WS_RM       (WS_CS + 4096)            // 64
#define WS_RS       (WS_RM + 64)              // 64
#define WS_Q2HL     (WS_RS + 64)              // q2h+q2l: 2*131072 ushorts = 131,072 floats
// sub-allocations inside the PART region:
#define WSP_CAND    200000                    // 64*64 ints
#define WSP_RVAL    220000                    // 64*64 floats
#define WSP_TIDX    240000                    // 64*50 ints

typedef short s16x8 __attribute__((ext_vector_type(8)));
typedef float f32x4 __attribute__((ext_vector_type(4)));

// ---------------------------------------------------------------------------
// bf16 split helpers: x ~= hi + lo, both RNE bf16.
// ---------------------------------------------------------------------------
__device__ __forceinline__ unsigned short bf16_rne(float x)
{
    unsigned int b = __float_as_uint(x);
    b += 0x7FFFu + ((b >> 16) & 1u);
    return (unsigned short)(b >> 16);
}
__device__ __forceinline__ float bf16_tof(unsigned short h)
{
    return __uint_as_float(((unsigned int)h) << 16);
}

// ---------------------------------------------------------------------------
// MLP GEMM, pipelined fp32 (kept fp32 deliberately — q2 accuracy gates the
// topk-index ordering). C_partial[kc][64][N] = A[64][Kc] @ W[Kc][N]
// ---------------------------------------------------------------------------
__global__ __launch_bounds__(256) void gemm64p_kernel(
    const float* __restrict__ A, const float* __restrict__ W,
    float* __restrict__ part, int K, int N, int kcK, int nBlocks)
{
    __shared__ float As[2][32][68];   // [buf][k][m]
    __shared__ float Bs[2][32][68];   // [buf][k][n]

    const int tid = threadIdx.x;
    const int nb = blockIdx.x % nBlocks;
    const int kc = blockIdx.x / nBlocks;
    const int kbeg = kc * kcK;

    const int tidm = tid >> 4;          // 0..15
    const int tidn = tid & 15;          // 0..15
    const int m0 = tidm * 4;
    const int n0 = tidn * 4;

    const int ar0 = tid >> 3, ac0 = tid & 7;    // + second A float4 at row ar0+32
    const int wr0 = tid >> 4, wc0 = tid & 15;   // + second B float4 at k-row wr0+16

    const float* Aptr0 = A + (size_t)ar0 * K + kbeg + ac0 * 4;
    const float* Aptr1 = A + (size_t)(ar0 + 32) * K + kbeg + ac0 * 4;
    const float* Wptr0 = W + (size_t)(kbeg + wr0) * N + nb * 64 + wc0 * 4;
    const float* Wptr1 = W + (size_t)(kbeg + wr0 + 16) * N + nb * 64 + wc0 * 4;

    float acc[4][4];
#pragma unroll
    for (int i = 0; i < 4; ++i)
#pragma unroll
        for (int j = 0; j < 4; ++j) acc[i][j] = 0.f;

    float4 pa0 = *(const float4*)(Aptr0);
    float4 pa1 = *(const float4*)(Aptr1);
    float4 pb0 = *(const float4*)(Wptr0);
    float4 pb1 = *(const float4*)(Wptr1);

    const int nsteps = kcK / 32;
    for (int s = 0; s < nsteps; ++s) {
        const int buf = s & 1;
        As[buf][ac0 * 4 + 0][ar0] = pa0.x;
        As[buf][ac0 * 4 + 1][ar0] = pa0.y;
        As[buf][ac0 * 4 + 2][ar0] = pa0.z;
        As[buf][ac0 * 4 + 3][ar0] = pa0.w;
        As[buf][ac0 * 4 + 0][ar0 + 32] = pa1.x;
        As[buf][ac0 * 4 + 1][ar0 + 32] = pa1.y;
        As[buf][ac0 * 4 + 2][ar0 + 32] = pa1.z;
        As[buf][ac0 * 4 + 3][ar0 + 32] = pa1.w;
        *(float4*)&Bs[buf][wr0][wc0 * 4] = pb0;
        *(float4*)&Bs[buf][wr0 + 16][wc0 * 4] = pb1;
        if (s + 1 < nsteps) {
            const int ko = 32 * (s + 1);
            pa0 = *(const float4*)(Aptr0 + ko);
            pa1 = *(const float4*)(Aptr1 + ko);
            pb0 = *(const float4*)(Wptr0 + (size_t)ko * N);
            pb1 = *(const float4*)(Wptr1 + (size_t)ko * N);
        }
        __syncthreads();
#pragma unroll
        for (int kk = 0; kk < 32; ++kk) {
            float4 a = *(const float4*)&As[buf][kk][m0];
            float4 b = *(const float4*)&Bs[buf][kk][n0];
            float av[4] = {a.x, a.y, a.z, a.w};
            float bv[4] = {b.x, b.y, b.z, b.w};
#pragma unroll
            for (int i = 0; i < 4; ++i)
#pragma unroll
                for (int j = 0; j < 4; ++j)
                    acc[i][j] += av[i] * bv[j];
        }
    }

#pragma unroll
    for (int i = 0; i < 4; ++i) {
        float4 v;
        v.x = acc[i][0]; v.y = acc[i][1]; v.z = acc[i][2]; v.w = acc[i][3];
        *(float4*)(part + (size_t)(kc * B + m0 + i) * N + nb * 64 + n0) = v;
    }
}

// Reduce K-chunk partials + bias (+ optional exact GELU).
// When uh/ul are non-null (layer 2), also emits the bf16 hi/lo split of out.
__global__ void mlp_reduce_kernel(const float* __restrict__ part,
                                  const float* __restrict__ bias,
                                  float* __restrict__ out, int N, int nchunks, int gelu,
                                  unsigned short* __restrict__ uh,
                                  unsigned short* __restrict__ ul)
{
    int e = blockIdx.x * 256 + threadIdx.x;   // over B*N
    int b = e / N, j = e - b * N;
    float s = bias[j];
    for (int c = 0; c < nchunks; ++c)
        s += part[(size_t)(c * B + b) * N + j];
    if (gelu)
        s = 0.5f * s * (1.0f + erff(s * 0.70710678118654752f));
    out[e] = s;
    if (uh) {
        unsigned short h = bf16_rne(s);
        uh[e] = h;
        ul[e] = bf16_rne(s - bf16_tof(h));
    }
}

// int64-layout hedge for vritti_types (values 0..4 -> high words all zero)
__device__ __forceinline__ bool types_is_i64(const int* t)
{
    int acc = 0;
#pragma unroll
    for (int j = 0; j < 16; ++j) acc |= t[2 * j + 1];
    return acc == 0;
}

// ---------------------------------------------------------------------------
// sims via split-bf16 MFMA — CHUNKED LDS A-staging + free-running B pipeline.
// logits = (q2 @ seed^T)*gate + vbias[type]
// grid = 782 (64-col tiles), 256 threads = 4 waves; wave w owns 16 seed cols.
// A (q2 hi/lo) staged in 8 chunks of 256-K into LDS (64 KB, single-buffered)
// -> only 2 barriers per chunk (16/block vs round-6's 32). Between barriers,
// 4 phases of 64-K MFMA run with the depth-2 B register pipeline completely
// free of vmcnt drains (the m97 barrier-drain can only bite twice per 256 K).
// LDS layout is FRAGMENT-MAJOR ([kseg][row][8 shorts]): both ds_write_b128
// and ds_read_b128 land 2 lanes/bank (free, m136) — no padding, no swizzle.
// B (seed, HBM, read-once) prefetched 2 phases (~1200 cyc) ahead.
// ---------------------------------------------------------------------------
__global__ __launch_bounds__(256) void sims_mfma_kernel(
    const unsigned short* __restrict__ q2h, const unsigned short* __restrict__ q2l,
    const float* __restrict__ seed,
    const float* __restrict__ karma, const int* __restrict__ types,
    const float* __restrict__ vbias, float* __restrict__ logits)
{
    // 32 ksegs x 64 rows x 8 shorts = 32 KB per array
    __shared__ __align__(16) unsigned short Ash[32 * 64 * 8];
    __shared__ __align__(16) unsigned short Asl[32 * 64 * 8];

    const int tid = threadIdx.x;
    const int n0 = blockIdx.x * 64;
    const int lane = tid & 63;
    const int wv  = tid >> 6;       // 0..3: n-tile of this wave
    const int l15 = lane & 15;
    const int lg  = lane >> 4;      // k-group 0..3

    const int srow = tid >> 2;      // A staging row 0..63
    const int seg  = tid & 3;       // A staging segment (64 shorts = 8 frags)

    const int nrow = n0 + wv * 16 + l15;            // seed row this lane owns
    const bool nvalid = nrow < NSEED;
    const float* brow = seed + (size_t)nrow * D + 8 * lg;
    const unsigned short* gh = q2h + (size_t)srow * D + seg * 64;
    const unsigned short* gl = q2l + (size_t)srow * D + seg * 64;

    f32x4 acc[4];
#pragma unroll
    for (int t = 0; t < 4; ++t) acc[t] = (f32x4){0.f, 0.f, 0.f, 0.f};

    // -------- B pipeline registers (2 sets, static names, depth 2) --------
    float4 b00, b01, b02, b03;      // even phases: k +[0,4,32,36]
    float4 b10, b11, b12, b13;      // odd phases
    b00 = b01 = b02 = b03 = make_float4(0.f, 0.f, 0.f, 0.f);
    b10 = b11 = b12 = b13 = make_float4(0.f, 0.f, 0.f, 0.f);
    if (nvalid) {
        b00 = *(const float4*)(brow);      b01 = *(const float4*)(brow + 4);
        b02 = *(const float4*)(brow + 32); b03 = *(const float4*)(brow + 36);
        b10 = *(const float4*)(brow + 64); b11 = *(const float4*)(brow + 68);
        b12 = *(const float4*)(brow + 96); b13 = *(const float4*)(brow + 100);
    }

#define SIMS_CONV(F0, F1, BH, BL)                                          \
    {                                                                      \
        float xs[8] = {F0.x, F0.y, F0.z, F0.w, F1.x, F1.y, F1.z, F1.w};    \
        _Pragma("unroll")                                                  \
        for (int j = 0; j < 8; ++j) {                                      \
            unsigned short hu = bf16_rne(xs[j]);                           \
            BH[j] = (short)hu;                                             \
            BL[j] = (short)bf16_rne(xs[j] - bf16_tof(hu));                 \
        }                                                                  \
    }

    // One half-step (32 K): fragment-major LDS reads + 12 MFMA
#define SIMS_HALF(P, KS, BH, BL)                                           \
    {                                                                      \
        s16x8 ah[4], al[4];                                                \
        _Pragma("unroll")                                                  \
        for (int t = 0; t < 4; ++t) {                                      \
            const int fi = ((((P) * 8 + (KS) * 4 + lg) * 64) + t * 16 + l15) * 8; \
            ah[t] = *(const s16x8*)&Ash[fi];                               \
            al[t] = *(const s16x8*)&Asl[fi];                               \
        }                                                                  \
        _Pragma("unroll")                                                  \
        for (int t = 0; t < 4; ++t) {                                      \
            acc[t] = __builtin_amdgcn_mfma_f32_16x16x32_bf16(ah[t], BH, acc[t], 0, 0, 0); \
            acc[t] = __builtin_amdgcn_mfma_f32_16x16x32_bf16(al[t], BH, acc[t], 0, 0, 0); \
            acc[t] = __builtin_amdgcn_mfma_f32_16x16x32_bf16(ah[t], BL, acc[t], 0, 0, 0); \
        }                                                                  \
    }

    // One phase (64 K at kb = c*256 + P*64): prefetch B for phase+2, compute
#define SIMS_PHASE(P, B0, B1, B2, B3)                                      \
    {                                                                      \
        const int kb = c * 256 + (P) * 64;                                 \
        float4 pna = make_float4(0.f, 0.f, 0.f, 0.f);                      \
        float4 pnb = pna, pnc = pna, pnd = pna;                            \
        if (kb + 128 < D && nvalid) {                                      \
            pna = *(const float4*)(brow + kb + 128);                       \
            pnb = *(const float4*)(brow + kb + 132);                       \
            pnc = *(const float4*)(brow + kb + 160);                       \
            pnd = *(const float4*)(brow + kb + 164);                       \
        }                                                                  \
        s16x8 bh, bl;                                                      \
        SIMS_CONV(B0, B1, bh, bl);                                         \
        SIMS_HALF(P, 0, bh, bl);                                           \
        SIMS_CONV(B2, B3, bh, bl);                                         \
        SIMS_HALF(P, 1, bh, bl);                                           \
        B0 = pna; B1 = pnb; B2 = pnc; B3 = pnd;                            \
    }

    for (int c = 0; c < 8; ++c) {
        __syncthreads();   // WAR: all waves done reading chunk c-1
        {   // stage A chunk c (fragment-major; conflict-free writes)
            const unsigned short* ph = gh + c * 256;
            const unsigned short* pl = gl + c * 256;
            s16x8 th[8], tl[8];
#pragma unroll
            for (int i = 0; i < 8; ++i) th[i] = *(const s16x8*)(ph + i * 8);
#pragma unroll
            for (int i = 0; i < 8; ++i) tl[i] = *(const s16x8*)(pl + i * 8);
#pragma unroll
            for (int i = 0; i < 8; ++i) {
                const int fi = ((seg * 8 + i) * 64 + srow) * 8;
                *(s16x8*)&Ash[fi] = th[i];
                *(s16x8*)&Asl[fi] = tl[i];
            }
        }
        __syncthreads();   // staging visible
        SIMS_PHASE(0, b00, b01, b02, b03);
        SIMS_PHASE(1, b10, b11, b12, b13);
        SIMS_PHASE(2, b00, b01, b02, b03);
        SIMS_PHASE(3, b10, b11, b12, b13);
    }
#undef SIMS_CONV
#undef SIMS_HALF
#undef SIMS_PHASE

    // epilogue: gate + vritti bias. D layout: col=lane&15, row=4*lg+reg.
    if (nvalid) {
        const bool i64 = types_is_i64(types);
        float ka = karma[nrow];
        float gate = 1.0f / (1.0f + expf(-(ka + 0.3f) * 10.0f));
        int ty = i64 ? types[2 * nrow] : types[nrow];
        float bias = vbias[ty];
#pragma unroll
        for (int t = 0; t < 4; ++t) {
#pragma unroll
            for (int r = 0; r < 4; ++r) {
                int m = t * 16 + lg * 4 + r;
                logits[(size_t)m * NSEED + nrow] = acc[t][r] * gate + bias;
            }
        }
    }
}

// ---------------------------------------------------------------------------
// Per-(row,chunk): online softmax partial (m,s) + chunk top-CEMIT.
// grid = 64 rows * 64 chunks, 64 threads (1 wave).
// ---------------------------------------------------------------------------
__global__ __launch_bounds__(64) void chunk_topk_kernel(
    const float* __restrict__ logits,
    float* __restrict__ chunk_m, float* __restrict__ chunk_s,
    float* __restrict__ cand_val, int* __restrict__ cand_idx)
{
    const int bid = blockIdx.x;
    const int row = bid >> 6, chunk = bid & 63;
    const int start = chunk * CHUNK_SZ;
    const int end = min(start + CHUNK_SZ, NSEED);
    const int lane = threadIdx.x;
    const float* Lrow = logits + (size_t)row * NSEED;

    float v[13];
#pragma unroll
    for (int j = 0; j < 13; ++j) {
        int e = start + lane + j * 64;
        v[j] = (e < end) ? Lrow[e] : -INFINITY;
    }

    // online (m, s) partial: s = sum exp(2*(l - m))
    float m = v[0];
#pragma unroll
    for (int j = 1; j < 13; ++j) m = fmaxf(m, v[j]);
    float s = 0.f;
#pragma unroll
    for (int j = 0; j < 13; ++j) s += expf(2.f * (v[j] - m));
#pragma unroll
    for (int d = 1; d < 64; d <<= 1) {
        float mo = __shfl_xor(m, d);
        float so = __shfl_xor(s, d);
        float nm = fmaxf(m, mo);
        s = s * expf(2.f * (m - nm)) + so * expf(2.f * (mo - nm));
        m = nm;
    }
    if (lane == 0) { chunk_m[bid] = m; chunk_s[bid] = s; }

    // chunk top-CEMIT via wave-argmax iterations (lower index wins ties)
    for (int it = 0; it < CEMIT; ++it) {
        float bv = v[0]; int bj = 0;
#pragma unroll
        for (int j = 1; j < 13; ++j)
            if (v[j] > bv) { bv = v[j]; bj = j; }
        int bi = start + lane + bj * 64;
#pragma unroll
        for (int d = 1; d < 64; d <<= 1) {
            float ov = __shfl_xor(bv, d);
            int oi = __shfl_xor(bi, d);
            if (ov > bv || (ov == bv && oi < bi)) { bv = ov; bi = oi; }
        }
        if (lane == 0) {
            cand_val[bid * CEMIT + it] = bv;
            cand_idx[bid * CEMIT + it] = bi;
        }
#pragma unroll
        for (int j = 0; j < 13; ++j)
            if (start + lane + j * 64 == bi) v[j] = -INFINITY;
    }
}

// ---------------------------------------------------------------------------
// Per-row merge: 64 (m,s) partials -> (M, 1/S); 1280 candidates -> top-NCAND
// candidate indices (by MFMA logit; candidate set, not final order).
// ---------------------------------------------------------------------------
__global__ __launch_bounds__(256) void merge_topk_kernel(
    const float* __restrict__ chunk_m, const float* __restrict__ chunk_s,
    const float* __restrict__ cand_val, const int* __restrict__ cand_idx,
    float* __restrict__ row_M, float* __restrict__ row_rS,
    int* __restrict__ cand2)
{
    const int row = blockIdx.x;
    const int tid = threadIdx.x;
    const int lane = tid & 63, wave = tid >> 6;
    __shared__ float rv[4];
    __shared__ int ri[4];

    if (wave == 0) {
        float m = chunk_m[row * 64 + lane];
        float s = chunk_s[row * 64 + lane];
#pragma unroll
        for (int d = 1; d < 64; d <<= 1) {
            float mo = __shfl_xor(m, d);
            float so = __shfl_xor(s, d);
            float nm = fmaxf(m, mo);
            s = s * expf(2.f * (m - nm)) + so * expf(2.f * (mo - nm));
            m = nm;
        }
        if (lane == 0) { row_M[row] = m; row_rS[row] = 1.0f / s; }
    }

    float v[5]; int ix[5];
#pragma unroll
    for (int j = 0; j < 5; ++j) {
        int e = tid + j * 256;                      // 1280 = NCHUNKS*CEMIT
        v[j] = cand_val[row * (NCHUNKS * CEMIT) + e];
        ix[j] = cand_idx[row * (NCHUNKS * CEMIT) + e];
    }

    for (int it = 0; it < NCAND; ++it) {
        float bv = v[0]; int bi = ix[0];
#pragma unroll
        for (int j = 1; j < 5; ++j)
            if (v[j] > bv || (v[j] == bv && ix[j] < bi)) { bv = v[j]; bi = ix[j]; }
#pragma unroll
        for (int d = 1; d < 64; d <<= 1) {
            float ov = __shfl_xor(bv, d);
            int oi = __shfl_xor(bi, d);
            if (ov > bv || (ov == bv && oi < bi)) { bv = ov; bi = oi; }
        }
        if (lane == 0) { rv[wave] = bv; ri[wave] = bi; }
        __syncthreads();
        float wv = rv[0]; int wi = ri[0];
#pragma unroll
        for (int w = 1; w < 4; ++w)
            if (rv[w] > wv || (rv[w] == wv && ri[w] < wi)) { wv = rv[w]; wi = ri[w]; }
        __syncthreads();
        if (tid == 0) cand2[row * NCAND + it] = wi;
#pragma unroll
        for (int j = 0; j < 5; ++j)
            if (ix[j] == wi) v[j] = -INFINITY;
    }
}

// ---------------------------------------------------------------------------
// Exact rescore of candidates: fp64 dot(q2[row], seed[idx]) + fp32 gate/bias.
// grid = (NCAND/4, 64 rows), 256 threads = 4 waves (one candidate per wave).
// ---------------------------------------------------------------------------
__global__ __launch_bounds__(256) void rescore_kernel(
    const float* __restrict__ q2, const float* __restrict__ seed,
    const float* __restrict__ karma, const int* __restrict__ types,
    const float* __restrict__ vbias, const int* __restrict__ cand2,
    float* __restrict__ rvals)
{
    const int row = blockIdx.y;
    const int wv = threadIdx.x >> 6, lane = threadIdx.x & 63;
    const int ci = blockIdx.x * 4 + wv;             // 0..NCAND-1
    const int idx = cand2[row * NCAND + ci];
    const float* qrow = q2 + (size_t)row * D;
    const float* srow = seed + (size_t)idx * D;

    double s = 0.0;
#pragma unroll
    for (int i = 0; i < 8; ++i) {
        float4 a = *(const float4*)(qrow + lane * 4 + i * 256);
        float4 b = *(const float4*)(srow + lane * 4 + i * 256);
        s += (double)a.x * (double)b.x + (double)a.y * (double)b.y
           + (double)a.z * (double)b.z + (double)a.w * (double)b.w;
    }
#pragma unroll
    for (int d = 1; d < 64; d <<= 1) s += __shfl_xor(s, d);

    if (lane == 0) {
        float ka = karma[idx];
        float gate = 1.0f / (1.0f + expf(-(ka + 0.3f) * 10.0f));
        bool i64 = types_is_i64(types);
        int ty = i64 ? types[2 * idx] : types[idx];
        rvals[row * NCAND + ci] = (float)s * gate + vbias[ty];
    }
}

// ---------------------------------------------------------------------------
// Final per-row top-50 (sorted desc, lower index on ties) from NCAND rescored.
// grid = 64, 64 threads (1 wave, one candidate per lane).
// ---------------------------------------------------------------------------
__global__ __launch_bounds__(64) void final50_kernel(
    const float* __restrict__ rvals, const int* __restrict__ cand2,
    float* __restrict__ out_idx_f, int* __restrict__ topk_idx)
{
    const int row = blockIdx.x;
    const int lane = threadIdx.x;

    float v = rvals[row * NCAND + lane];
    int ix = cand2[row * NCAND + lane];

    for (int it = 0; it < KTOP; ++it) {
        float bv = v; int bi = ix;
#pragma unroll
        for (int d = 1; d < 64; d <<= 1) {
            float ov = __shfl_xor(bv, d);
            int oi = __shfl_xor(bi, d);
            if (ov > bv || (ov == bv && oi < bi)) { bv = ov; bi = oi; }
        }
        if (lane == 0) {
            out_idx_f[row * KTOP + it] = (float)bi;
            topk_idx[row * KTOP + it] = bi;
        }
        if (ix == bi) v = -INFINITY;
    }
}

// attention weights: w = exp(2*(l - M)) / S
__global__ void weights_kernel(const float* __restrict__ logits,
                               const float* __restrict__ row_M,
                               const float* __restrict__ row_rS,
                               float* __restrict__ attn)
{
    const int row = blockIdx.y;
    const int f = blockIdx.x * 256 + threadIdx.x;
    if (f >= NSEED / 4) return;
    const float M = row_M[row], rS = row_rS[row];
    float4 l = ((const float4*)(logits + (size_t)row * NSEED))[f];
    float4 w;
    w.x = expf(2.f * (l.x - M)) * rS;
    w.y = expf(2.f * (l.y - M)) * rS;
    w.z = expf(2.f * (l.z - M)) * rS;
    w.w = expf(2.f * (l.w - M)) * rS;
    ((float4*)(attn + (size_t)row * NSEED))[f] = w;
}

// chitta gather: 2048 floats per (row,k)
__global__ void gather_kernel(const float* __restrict__ seed,
                              const int* __restrict__ topk_idx,
                              float* __restrict__ chitta)
{
    const int k = blockIdx.x, row = blockIdx.y;
    const int idx = topk_idx[row * KTOP + k];
    const float4* src = (const float4*)(seed + (size_t)idx * D);
    float4* dst = (float4*)(chitta + (size_t)(row * KTOP + k) * D);
#pragma unroll
    for (int j = 0; j < 2; ++j)
        dst[threadIdx.x + j * 256] = src[threadIdx.x + j * 256];
}

extern "C" void kernel_launch(void* const* d_in, const int* in_sizes, int n_in,
                              void* d_out, int out_size, void* d_ws, size_t ws_size,
                              hipStream_t stream)
{
    const float* query = (const float*)d_in[0];
    const int*   types = (const int*)d_in[1];
    const float* seed  = (const float*)d_in[2];
    const float* karma = (const float*)d_in[3];
    const float* vbias = (const float*)d_in[4];
    const float* W1    = (const float*)d_in[5];
    const float* b1    = (const float*)d_in[6];
    const float* W2    = (const float*)d_in[7];
    const float* b2    = (const float*)d_in[8];

    float* ws = (float*)d_ws;
    float* logits = ws + WS_LOGITS;   // also MLP partial buffer (freed before sims)
    float* h      = ws + WS_H;
    float* q2     = ws + WS_Q2;
    float* part   = ws + WS_PART;
    float* cval   = ws + WS_CVAL;
    int*   cidx   = (int*)(ws + WS_CIDX);
    float* cm     = ws + WS_CM;
    float* cs     = ws + WS_CS;
    float* rM     = ws + WS_RM;
    float* rS     = ws + WS_RS;

    // q2 bf16 hi/lo live in their own region (written by fused mlp_reduce L2)
    unsigned short* q2h = (unsigned short*)(ws + WS_Q2HL);   // 64*2048 ushorts
    unsigned short* q2l = q2h + (size_t)B * D;

    // sub-allocations inside PART:
    int*   cand2 = (int*)(part + WSP_CAND);                   // 64*64
    float* rvals = part + WSP_RVAL;                           // 64*64
    int*   tidx  = (int*)(part + WSP_TIDX);                   // 64*50

    float* outv   = (float*)d_out;
    float* chitta = outv;                                   // [64][50][2048]
    float* attn   = outv + (size_t)B * KTOP * D;            // [64][50000]
    float* oidxf  = attn + (size_t)B * NSEED;               // [64][50] as float

    // MLP layer 1: 64 n-blocks x 8 k-chunks (kcK=256) -> 512 blocks, 2/CU
    gemm64p_kernel<<<64 * 8, 256, 0, stream>>>(query, W1, logits, D, H, 256, 64);
    mlp_reduce_kernel<<<(B * H) / 256, 256, 0, stream>>>(logits, b1, h, H, 8, 1, nullptr, nullptr);
    // MLP layer 2: 32 n-blocks x 16 k-chunks (kcK=256) -> 512 blocks, 2/CU; fused q2 split
    gemm64p_kernel<<<32 * 16, 256, 0, stream>>>(h, W2, logits, H, D, 256, 32);
    mlp_reduce_kernel<<<(B * D) / 256, 256, 0, stream>>>(logits, b2, q2, D, 16, 0, q2h, q2l);
    // similarity + gate + bias -> logits (chunked-LDS + free-running B pipeline)
    sims_mfma_kernel<<<(NSEED + 63) / 64, 256, 0, stream>>>(q2h, q2l, seed, karma, types, vbias, logits);
    // per-chunk stats + top-20 candidates
    chunk_topk_kernel<<<B * NCHUNKS, 64, 0, stream>>>(logits, cm, cs, cval, cidx);
    // per-row merge -> (M, 1/S) + top-NCAND candidate set
    merge_topk_kernel<<<B, 256, 0, stream>>>(cm, cs, cval, cidx, rM, rS, cand2);
    // exact fp64 rescore of candidates
    rescore_kernel<<<dim3(NCAND / 4, B), 256, 0, stream>>>(q2, seed, karma, types, vbias, cand2, rvals);
    // final sorted top-50 indices
    final50_kernel<<<B, 64, 0, stream>>>(rvals, cand2, oidxf, tidx);
    // full attention weights
    weights_kernel<<<dim3((NSEED / 4 + 255) / 256, B), 256, 0, stream>>>(logits, rM, rS, attn);
    // retrieved embeddings
    gather_kernel<<<dim3(KTOP, B), 256, 0, stream>>>(seed, tidx, chitta);
}

// Round 10
// 320.503 us; speedup vs baseline: 1.5422x; 1.0838x over previous
//
#include <hip/hip_runtime.h>
#include <math.h>

// Problem constants
#define B 64
#define D 2048
#define H 4096
#define NSEED 50000
#define KTOP 50
#define NCAND 64            // rescored candidates per row
#define CEMIT 20            // candidates emitted per chunk (P(chunk holds >20 of top-64) ~ 2e-20)
#define NCHUNKS 64          // topk chunks per row
#define CHUNK_SZ 782        // ceil(50000/64)

// ws layout (float offsets)
#define WS_LOGITS   0                         // 64*50000 = 3,200,000 (also MLP partials)
#define WS_H        3200000                   // 64*4096  = 262,144
#define WS_Q2       (WS_H + B*H)              // 64*2048  = 131,072
#define WS_PART     (WS_Q2 + B*D)             // 1,048,576 (cand/rvals/tidx live here)
#define WS_CVAL     (WS_PART + 1048576)       // 64*64*20 = 81,920 (region sized 262,144)
#define WS_CIDX     (WS_CVAL + 262144)        // ints
#define WS_CM       (WS_CIDX + 262144)        // 4096
#define WS_CS       (WS_CM + 4096)            // 4096
#define WS_RM       (WS_CS + 4096)            // 64
#define WS_RS       (WS_RM + 64)              // 64
#define WS_Q2HL     (WS_RS + 64)              // q2h+q2l: 2*131072 ushorts = 131,072 floats
// sub-allocations inside the PART region:
#define WSP_CAND    200000                    // 64*64 ints
#define WSP_RVAL    220000                    // 64*64 floats
#define WSP_TIDX    240000                    // 64*50 ints

typedef short s16x8 __attribute__((ext_vector_type(8)));
typedef float f32x4 __attribute__((ext_vector_type(4)));

// ---------------------------------------------------------------------------
// bf16 split helpers: x ~= hi + lo, both RNE bf16.
// ---------------------------------------------------------------------------
__device__ __forceinline__ unsigned short bf16_rne(float x)
{
    unsigned int b = __float_as_uint(x);
    b += 0x7FFFu + ((b >> 16) & 1u);
    return (unsigned short)(b >> 16);
}
__device__ __forceinline__ float bf16_tof(unsigned short h)
{
    return __uint_as_float(((unsigned int)h) << 16);
}

// ---------------------------------------------------------------------------
// MLP GEMM, pipelined fp32 (kept fp32 deliberately — q2 accuracy gates the
// topk-index ordering). C_partial[kc][64][N] = A[64][Kc] @ W[Kc][N]
// (exact round-7 configuration — known-good 316 us baseline)
// ---------------------------------------------------------------------------
__global__ __launch_bounds__(256) void gemm64p_kernel(
    const float* __restrict__ A, const float* __restrict__ W,
    float* __restrict__ part, int K, int N, int kcK, int nBlocks)
{
    __shared__ float As[2][32][68];   // [buf][k][m]
    __shared__ float Bs[2][32][68];   // [buf][k][n]

    const int tid = threadIdx.x;
    const int nb = blockIdx.x % nBlocks;
    const int kc = blockIdx.x / nBlocks;
    const int kbeg = kc * kcK;

    const int tidm = tid >> 4;          // 0..15
    const int tidn = tid & 15;          // 0..15
    const int m0 = tidm * 4;
    const int n0 = tidn * 4;

    const int ar0 = tid >> 3, ac0 = tid & 7;    // + second A float4 at row ar0+32
    const int wr0 = tid >> 4, wc0 = tid & 15;   // + second B float4 at k-row wr0+16

    const float* Aptr0 = A + (size_t)ar0 * K + kbeg + ac0 * 4;
    const float* Aptr1 = A + (size_t)(ar0 + 32) * K + kbeg + ac0 * 4;
    const float* Wptr0 = W + (size_t)(kbeg + wr0) * N + nb * 64 + wc0 * 4;
    const float* Wptr1 = W + (size_t)(kbeg + wr0 + 16) * N + nb * 64 + wc0 * 4;

    float acc[4][4];
#pragma unroll
    for (int i = 0; i < 4; ++i)
#pragma unroll
        for (int j = 0; j < 4; ++j) acc[i][j] = 0.f;

    float4 pa0 = *(const float4*)(Aptr0);
    float4 pa1 = *(const float4*)(Aptr1);
    float4 pb0 = *(const float4*)(Wptr0);
    float4 pb1 = *(const float4*)(Wptr1);

    const int nsteps = kcK / 32;
    for (int s = 0; s < nsteps; ++s) {
        const int buf = s & 1;
        As[buf][ac0 * 4 + 0][ar0] = pa0.x;
        As[buf][ac0 * 4 + 1][ar0] = pa0.y;
        As[buf][ac0 * 4 + 2][ar0] = pa0.z;
        As[buf][ac0 * 4 + 3][ar0] = pa0.w;
        As[buf][ac0 * 4 + 0][ar0 + 32] = pa1.x;
        As[buf][ac0 * 4 + 1][ar0 + 32] = pa1.y;
        As[buf][ac0 * 4 + 2][ar0 + 32] = pa1.z;
        As[buf][ac0 * 4 + 3][ar0 + 32] = pa1.w;
        *(float4*)&Bs[buf][wr0][wc0 * 4] = pb0;
        *(float4*)&Bs[buf][wr0 + 16][wc0 * 4] = pb1;
        if (s + 1 < nsteps) {
            const int ko = 32 * (s + 1);
            pa0 = *(const float4*)(Aptr0 + ko);
            pa1 = *(const float4*)(Aptr1 + ko);
            pb0 = *(const float4*)(Wptr0 + (size_t)ko * N);
            pb1 = *(const float4*)(Wptr1 + (size_t)ko * N);
        }
        __syncthreads();
#pragma unroll
        for (int kk = 0; kk < 32; ++kk) {
            float4 a = *(const float4*)&As[buf][kk][m0];
            float4 b = *(const float4*)&Bs[buf][kk][n0];
            float av[4] = {a.x, a.y, a.z, a.w};
            float bv[4] = {b.x, b.y, b.z, b.w};
#pragma unroll
            for (int i = 0; i < 4; ++i)
#pragma unroll
                for (int j = 0; j < 4; ++j)
                    acc[i][j] += av[i] * bv[j];
        }
    }

#pragma unroll
    for (int i = 0; i < 4; ++i) {
        float4 v;
        v.x = acc[i][0]; v.y = acc[i][1]; v.z = acc[i][2]; v.w = acc[i][3];
        *(float4*)(part + (size_t)(kc * B + m0 + i) * N + nb * 64 + n0) = v;
    }
}

// Reduce K-chunk partials + bias (+ optional exact GELU).
// When uh/ul are non-null (layer 2), also emits the bf16 hi/lo split of out.
__global__ void mlp_reduce_kernel(const float* __restrict__ part,
                                  const float* __restrict__ bias,
                                  float* __restrict__ out, int N, int nchunks, int gelu,
                                  unsigned short* __restrict__ uh,
                                  unsigned short* __restrict__ ul)
{
    int e = blockIdx.x * 256 + threadIdx.x;   // over B*N
    int b = e / N, j = e - b * N;
    float s = bias[j];
    for (int c = 0; c < nchunks; ++c)
        s += part[(size_t)(c * B + b) * N + j];
    if (gelu)
        s = 0.5f * s * (1.0f + erff(s * 0.70710678118654752f));
    out[e] = s;
    if (uh) {
        unsigned short h = bf16_rne(s);
        uh[e] = h;
        ul[e] = bf16_rne(s - bf16_tof(h));
    }
}

// int64-layout hedge for vritti_types (values 0..4 -> high words all zero)
__device__ __forceinline__ bool types_is_i64(const int* t)
{
    int acc = 0;
#pragma unroll
    for (int j = 0; j < 16; ++j) acc |= t[2 * j + 1];
    return acc == 0;
}

// ---------------------------------------------------------------------------
// sims via split-bf16 MFMA, K-step 64, depth-2 register pipeline — round-6
// structure with ONE change: raw `s_barrier` + explicit `lgkmcnt(0)` instead
// of __syncthreads(). __syncthreads makes hipcc emit `s_waitcnt vmcnt(0)`
// before the barrier (m97 stall), draining the phase+2 A/B prefetches at all
// 32 barriers and collapsing the pipeline. The raw-asm barrier keeps them in
// flight; the ds_write of the 2-phase-old A regs gets a COUNTED vmcnt from
// the compiler's dependency tracking (T3/T4 counted-vmcnt idiom, m201/m218).
// Double-buffered LDS: phase p writes buf p&1, reads buf p&1; barrier at
// phase p separates phase p-1 reads from phase p+1 writes — 1 barrier/phase.
// ---------------------------------------------------------------------------
__global__ __launch_bounds__(256) void sims_mfma_kernel(
    const unsigned short* __restrict__ q2h, const unsigned short* __restrict__ q2l,
    const float* __restrict__ seed,
    const float* __restrict__ karma, const int* __restrict__ types,
    const float* __restrict__ vbias, float* __restrict__ logits)
{
    __shared__ __align__(16) unsigned short Ash[2][64][72];
    __shared__ __align__(16) unsigned short Asl[2][64][72];

    const int tid = threadIdx.x;
    const int n0 = blockIdx.x * 64;
    const int lane = tid & 63;
    const int wv  = tid >> 6;       // 0..3: n-tile of this wave
    const int l15 = lane & 15;
    const int lg  = lane >> 4;      // k-group 0..3

    const int srow = tid >> 2;      // A staging row 0..63
    const int seg  = tid & 3;       // A staging 16-short segment

    const int nrow = n0 + wv * 16 + l15;            // seed row this lane owns
    const bool nvalid = nrow < NSEED;
    const float* brow = seed + (size_t)nrow * D + 8 * lg;
    const size_t aoff = (size_t)srow * D + 16 * seg;

    f32x4 acc[4];
#pragma unroll
    for (int t = 0; t < 4; ++t) acc[t] = (f32x4){0.f, 0.f, 0.f, 0.f};

    // -------- pipeline registers (2 sets, static names) --------
    s16x8 a0ha, a0hb, a0la, a0lb;   // set 0 (even phases)
    s16x8 a1ha, a1hb, a1la, a1lb;   // set 1 (odd phases)
    float4 b00, b01, b02, b03;      // set 0 B: k +[0,4,32,36]
    float4 b10, b11, b12, b13;      // set 1 B

    // prologue: set0 <- phase 0 (kb=0), set1 <- phase 1 (kb=64)
    a0ha = *(const s16x8*)(q2h + aoff);
    a0hb = *(const s16x8*)(q2h + aoff + 8);
    a0la = *(const s16x8*)(q2l + aoff);
    a0lb = *(const s16x8*)(q2l + aoff + 8);
    a1ha = *(const s16x8*)(q2h + aoff + 64);
    a1hb = *(const s16x8*)(q2h + aoff + 72);
    a1la = *(const s16x8*)(q2l + aoff + 64);
    a1lb = *(const s16x8*)(q2l + aoff + 72);
    b00 = b01 = b02 = b03 = make_float4(0.f, 0.f, 0.f, 0.f);
    b10 = b11 = b12 = b13 = make_float4(0.f, 0.f, 0.f, 0.f);
    if (nvalid) {
        b00 = *(const float4*)(brow);      b01 = *(const float4*)(brow + 4);
        b02 = *(const float4*)(brow + 32); b03 = *(const float4*)(brow + 36);
        b10 = *(const float4*)(brow + 64); b11 = *(const float4*)(brow + 68);
        b12 = *(const float4*)(brow + 96); b13 = *(const float4*)(brow + 100);
    }

    // drain-free barrier: our ds_writes done (lgkmcnt), then s_barrier.
    // Single asm block with memory clobber = compiler cannot reorder LDS/mem
    // ops across it and does NOT insert vmcnt(0).
#define SIMS_BARRIER() asm volatile("s_waitcnt lgkmcnt(0)\n\ts_barrier" ::: "memory")

#define SIMS_CONV(F0, F1, BH, BL)                                          \
    {                                                                      \
        float xs[8] = {F0.x, F0.y, F0.z, F0.w, F1.x, F1.y, F1.z, F1.w};    \
        _Pragma("unroll")                                                  \
        for (int j = 0; j < 8; ++j) {                                      \
            unsigned short hu = bf16_rne(xs[j]);                           \
            BH[j] = (short)hu;                                             \
            BL[j] = (short)bf16_rne(xs[j] - bf16_tof(hu));                 \
        }                                                                  \
    }

#define SIMS_MFMA(BUF, KS, BH, BL)                                         \
    _Pragma("unroll")                                                      \
    for (int t = 0; t < 4; ++t) {                                          \
        s16x8 ah = *(const s16x8*)&Ash[BUF][t * 16 + l15][KS * 32 + 8 * lg]; \
        s16x8 al = *(const s16x8*)&Asl[BUF][t * 16 + l15][KS * 32 + 8 * lg]; \
        acc[t] = __builtin_amdgcn_mfma_f32_16x16x32_bf16(ah, BH, acc[t], 0, 0, 0); \
        acc[t] = __builtin_amdgcn_mfma_f32_16x16x32_bf16(al, BH, acc[t], 0, 0, 0); \
        acc[t] = __builtin_amdgcn_mfma_f32_16x16x32_bf16(ah, BL, acc[t], 0, 0, 0); \
    }

    for (int u = 0; u < 16; ++u) {
        // ================= phase 0: buffer 0, set 0 =================
        *(s16x8*)&Ash[0][srow][16 * seg]     = a0ha;
        *(s16x8*)&Ash[0][srow][16 * seg + 8] = a0hb;
        *(s16x8*)&Asl[0][srow][16 * seg]     = a0la;
        *(s16x8*)&Asl[0][srow][16 * seg + 8] = a0lb;
        float4 n0a = make_float4(0.f, 0.f, 0.f, 0.f), n0b = n0a, n0c = n0a, n0d = n0a;
        if (u < 15) {
            const int kb = 128 * u + 128;          // phase 2u+2
            a0ha = *(const s16x8*)(q2h + aoff + kb);
            a0hb = *(const s16x8*)(q2h + aoff + kb + 8);
            a0la = *(const s16x8*)(q2l + aoff + kb);
            a0lb = *(const s16x8*)(q2l + aoff + kb + 8);
            if (nvalid) {
                n0a = *(const float4*)(brow + kb);      n0b = *(const float4*)(brow + kb + 4);
                n0c = *(const float4*)(brow + kb + 32); n0d = *(const float4*)(brow + kb + 36);
            }
        }
        SIMS_BARRIER();
        {
            s16x8 bh, bl;
            SIMS_CONV(b00, b01, bh, bl);
            SIMS_MFMA(0, 0, bh, bl);
            SIMS_CONV(b02, b03, bh, bl);
            SIMS_MFMA(0, 1, bh, bl);
        }
        b00 = n0a; b01 = n0b; b02 = n0c; b03 = n0d;

        // ================= phase 1: buffer 1, set 1 =================
        *(s16x8*)&Ash[1][srow][16 * seg]     = a1ha;
        *(s16x8*)&Ash[1][srow][16 * seg + 8] = a1hb;
        *(s16x8*)&Asl[1][srow][16 * seg]     = a1la;
        *(s16x8*)&Asl[1][srow][16 * seg + 8] = a1lb;
        float4 n1a = make_float4(0.f, 0.f, 0.f, 0.f), n1b = n1a, n1c = n1a, n1d = n1a;
        if (u < 15) {
            const int kb = 128 * u + 192;          // phase 2u+3
            a1ha = *(const s16x8*)(q2h + aoff + kb);
            a1hb = *(const s16x8*)(q2h + aoff + kb + 8);
            a1la = *(const s16x8*)(q2l + aoff + kb);
            a1lb = *(const s16x8*)(q2l + aoff + kb + 8);
            if (nvalid) {
                n1a = *(const float4*)(brow + kb);      n1b = *(const float4*)(brow + kb + 4);
                n1c = *(const float4*)(brow + kb + 32); n1d = *(const float4*)(brow + kb + 36);
            }
        }
        SIMS_BARRIER();
        {
            s16x8 bh, bl;
            SIMS_CONV(b10, b11, bh, bl);
            SIMS_MFMA(1, 0, bh, bl);
            SIMS_CONV(b12, b13, bh, bl);
            SIMS_MFMA(1, 1, bh, bl);
        }
        b10 = n1a; b11 = n1b; b12 = n1c; b13 = n1d;
    }
#undef SIMS_CONV
#undef SIMS_MFMA
#undef SIMS_BARRIER

    // epilogue: gate + vritti bias. D layout: col=lane&15, row=4*lg+reg.
    if (nvalid) {
        const bool i64 = types_is_i64(types);
        float ka = karma[nrow];
        float gate = 1.0f / (1.0f + expf(-(ka + 0.3f) * 10.0f));
        int ty = i64 ? types[2 * nrow] : types[nrow];
        float bias = vbias[ty];
#pragma unroll
        for (int t = 0; t < 4; ++t) {
#pragma unroll
            for (int r = 0; r < 4; ++r) {
                int m = t * 16 + lg * 4 + r;
                logits[(size_t)m * NSEED + nrow] = acc[t][r] * gate + bias;
            }
        }
    }
}

// ---------------------------------------------------------------------------
// Per-(row,chunk): online softmax partial (m,s) + chunk top-CEMIT.
// grid = 64 rows * 64 chunks, 64 threads (1 wave).
// ---------------------------------------------------------------------------
__global__ __launch_bounds__(64) void chunk_topk_kernel(
    const float* __restrict__ logits,
    float* __restrict__ chunk_m, float* __restrict__ chunk_s,
    float* __restrict__ cand_val, int* __restrict__ cand_idx)
{
    const int bid = blockIdx.x;
    const int row = bid >> 6, chunk = bid & 63;
    const int start = chunk * CHUNK_SZ;
    const int end = min(start + CHUNK_SZ, NSEED);
    const int lane = threadIdx.x;
    const float* Lrow = logits + (size_t)row * NSEED;

    float v[13];
#pragma unroll
    for (int j = 0; j < 13; ++j) {
        int e = start + lane + j * 64;
        v[j] = (e < end) ? Lrow[e] : -INFINITY;
    }

    // online (m, s) partial: s = sum exp(2*(l - m))
    float m = v[0];
#pragma unroll
    for (int j = 1; j < 13; ++j) m = fmaxf(m, v[j]);
    float s = 0.f;
#pragma unroll
    for (int j = 0; j < 13; ++j) s += expf(2.f * (v[j] - m));
#pragma unroll
    for (int d = 1; d < 64; d <<= 1) {
        float mo = __shfl_xor(m, d);
        float so = __shfl_xor(s, d);
        float nm = fmaxf(m, mo);
        s = s * expf(2.f * (m - nm)) + so * expf(2.f * (mo - nm));
        m = nm;
    }
    if (lane == 0) { chunk_m[bid] = m; chunk_s[bid] = s; }

    // chunk top-CEMIT via wave-argmax iterations (lower index wins ties)
    for (int it = 0; it < CEMIT; ++it) {
        float bv = v[0]; int bj = 0;
#pragma unroll
        for (int j = 1; j < 13; ++j)
            if (v[j] > bv) { bv = v[j]; bj = j; }
        int bi = start + lane + bj * 64;
#pragma unroll
        for (int d = 1; d < 64; d <<= 1) {
            float ov = __shfl_xor(bv, d);
            int oi = __shfl_xor(bi, d);
            if (ov > bv || (ov == bv && oi < bi)) { bv = ov; bi = oi; }
        }
        if (lane == 0) {
            cand_val[bid * CEMIT + it] = bv;
            cand_idx[bid * CEMIT + it] = bi;
        }
#pragma unroll
        for (int j = 0; j < 13; ++j)
            if (start + lane + j * 64 == bi) v[j] = -INFINITY;
    }
}

// ---------------------------------------------------------------------------
// Per-row merge: 64 (m,s) partials -> (M, 1/S); 1280 candidates -> top-NCAND
// candidate indices (by MFMA logit; candidate set, not final order).
// ---------------------------------------------------------------------------
__global__ __launch_bounds__(256) void merge_topk_kernel(
    const float* __restrict__ chunk_m, const float* __restrict__ chunk_s,
    const float* __restrict__ cand_val, const int* __restrict__ cand_idx,
    float* __restrict__ row_M, float* __restrict__ row_rS,
    int* __restrict__ cand2)
{
    const int row = blockIdx.x;
    const int tid = threadIdx.x;
    const int lane = tid & 63, wave = tid >> 6;
    __shared__ float rv[4];
    __shared__ int ri[4];

    if (wave == 0) {
        float m = chunk_m[row * 64 + lane];
        float s = chunk_s[row * 64 + lane];
#pragma unroll
        for (int d = 1; d < 64; d <<= 1) {
            float mo = __shfl_xor(m, d);
            float so = __shfl_xor(s, d);
            float nm = fmaxf(m, mo);
            s = s * expf(2.f * (m - nm)) + so * expf(2.f * (mo - nm));
            m = nm;
        }
        if (lane == 0) { row_M[row] = m; row_rS[row] = 1.0f / s; }
    }

    float v[5]; int ix[5];
#pragma unroll
    for (int j = 0; j < 5; ++j) {
        int e = tid + j * 256;                      // 1280 = NCHUNKS*CEMIT
        v[j] = cand_val[row * (NCHUNKS * CEMIT) + e];
        ix[j] = cand_idx[row * (NCHUNKS * CEMIT) + e];
    }

    for (int it = 0; it < NCAND; ++it) {
        float bv = v[0]; int bi = ix[0];
#pragma unroll
        for (int j = 1; j < 5; ++j)
            if (v[j] > bv || (v[j] == bv && ix[j] < bi)) { bv = v[j]; bi = ix[j]; }
#pragma unroll
        for (int d = 1; d < 64; d <<= 1) {
            float ov = __shfl_xor(bv, d);
            int oi = __shfl_xor(bi, d);
            if (ov > bv || (ov == bv && oi < bi)) { bv = ov; bi = oi; }
        }
        if (lane == 0) { rv[wave] = bv; ri[wave] = bi; }
        __syncthreads();
        float wv = rv[0]; int wi = ri[0];
#pragma unroll
        for (int w = 1; w < 4; ++w)
            if (rv[w] > wv || (rv[w] == wv && ri[w] < wi)) { wv = rv[w]; wi = ri[w]; }
        __syncthreads();
        if (tid == 0) cand2[row * NCAND + it] = wi;
#pragma unroll
        for (int j = 0; j < 5; ++j)
            if (ix[j] == wi) v[j] = -INFINITY;
    }
}

// ---------------------------------------------------------------------------
// Exact rescore of candidates: fp64 dot(q2[row], seed[idx]) + fp32 gate/bias.
// grid = (NCAND/4, 64 rows), 256 threads = 4 waves (one candidate per wave).
// ---------------------------------------------------------------------------
__global__ __launch_bounds__(256) void rescore_kernel(
    const float* __restrict__ q2, const float* __restrict__ seed,
    const float* __restrict__ karma, const int* __restrict__ types,
    const float* __restrict__ vbias, const int* __restrict__ cand2,
    float* __restrict__ rvals)
{
    const int row = blockIdx.y;
    const int wv = threadIdx.x >> 6, lane = threadIdx.x & 63;
    const int ci = blockIdx.x * 4 + wv;             // 0..NCAND-1
    const int idx = cand2[row * NCAND + ci];
    const float* qrow = q2 + (size_t)row * D;
    const float* srow = seed + (size_t)idx * D;

    double s = 0.0;
#pragma unroll
    for (int i = 0; i < 8; ++i) {
        float4 a = *(const float4*)(qrow + lane * 4 + i * 256);
        float4 b = *(const float4*)(srow + lane * 4 + i * 256);
        s += (double)a.x * (double)b.x + (double)a.y * (double)b.y
           + (double)a.z * (double)b.z + (double)a.w * (double)b.w;
    }
#pragma unroll
    for (int d = 1; d < 64; d <<= 1) s += __shfl_xor(s, d);

    if (lane == 0) {
        float ka = karma[idx];
        float gate = 1.0f / (1.0f + expf(-(ka + 0.3f) * 10.0f));
        bool i64 = types_is_i64(types);
        int ty = i64 ? types[2 * idx] : types[idx];
        rvals[row * NCAND + ci] = (float)s * gate + vbias[ty];
    }
}

// ---------------------------------------------------------------------------
// Final per-row top-50 (sorted desc, lower index on ties) from NCAND rescored.
// grid = 64, 64 threads (1 wave, one candidate per lane).
// ---------------------------------------------------------------------------
__global__ __launch_bounds__(64) void final50_kernel(
    const float* __restrict__ rvals, const int* __restrict__ cand2,
    float* __restrict__ out_idx_f, int* __restrict__ topk_idx)
{
    const int row = blockIdx.x;
    const int lane = threadIdx.x;

    float v = rvals[row * NCAND + lane];
    int ix = cand2[row * NCAND + lane];

    for (int it = 0; it < KTOP; ++it) {
        float bv = v; int bi = ix;
#pragma unroll
        for (int d = 1; d < 64; d <<= 1) {
            float ov = __shfl_xor(bv, d);
            int oi = __shfl_xor(bi, d);
            if (ov > bv || (ov == bv && oi < bi)) { bv = ov; bi = oi; }
        }
        if (lane == 0) {
            out_idx_f[row * KTOP + it] = (float)bi;
            topk_idx[row * KTOP + it] = bi;
        }
        if (ix == bi) v = -INFINITY;
    }
}

// attention weights: w = exp(2*(l - M)) / S
__global__ void weights_kernel(const float* __restrict__ logits,
                               const float* __restrict__ row_M,
                               const float* __restrict__ row_rS,
                               float* __restrict__ attn)
{
    const int row = blockIdx.y;
    const int f = blockIdx.x * 256 + threadIdx.x;
    if (f >= NSEED / 4) return;
    const float M = row_M[row], rS = row_rS[row];
    float4 l = ((const float4*)(logits + (size_t)row * NSEED))[f];
    float4 w;
    w.x = expf(2.f * (l.x - M)) * rS;
    w.y = expf(2.f * (l.y - M)) * rS;
    w.z = expf(2.f * (l.z - M)) * rS;
    w.w = expf(2.f * (l.w - M)) * rS;
    ((float4*)(attn + (size_t)row * NSEED))[f] = w;
}

// chitta gather: 2048 floats per (row,k)
__global__ void gather_kernel(const float* __restrict__ seed,
                              const int* __restrict__ topk_idx,
                              float* __restrict__ chitta)
{
    const int k = blockIdx.x, row = blockIdx.y;
    const int idx = topk_idx[row * KTOP + k];
    const float4* src = (const float4*)(seed + (size_t)idx * D);
    float4* dst = (float4*)(chitta + (size_t)(row * KTOP + k) * D);
#pragma unroll
    for (int j = 0; j < 2; ++j)
        dst[threadIdx.x + j * 256] = src[threadIdx.x + j * 256];
}

extern "C" void kernel_launch(void* const* d_in, const int* in_sizes, int n_in,
                              void* d_out, int out_size, void* d_ws, size_t ws_size,
                              hipStream_t stream)
{
    const float* query = (const float*)d_in[0];
    const int*   types = (const int*)d_in[1];
    const float* seed  = (const float*)d_in[2];
    const float* karma = (const float*)d_in[3];
    const float* vbias = (const float*)d_in[4];
    const float* W1    = (const float*)d_in[5];
    const float* b1    = (const float*)d_in[6];
    const float* W2    = (const float*)d_in[7];
    const float* b2    = (const float*)d_in[8];

    float* ws = (float*)d_ws;
    float* logits = ws + WS_LOGITS;   // also MLP partial buffer (freed before sims)
    float* h      = ws + WS_H;
    float* q2     = ws + WS_Q2;
    float* part   = ws + WS_PART;
    float* cval   = ws + WS_CVAL;
    int*   cidx   = (int*)(ws + WS_CIDX);
    float* cm     = ws + WS_CM;
    float* cs     = ws + WS_CS;
    float* rM     = ws + WS_RM;
    float* rS     = ws + WS_RS;

    // q2 bf16 hi/lo live in their own region (written by fused mlp_reduce L2)
    unsigned short* q2h = (unsigned short*)(ws + WS_Q2HL);   // 64*2048 ushorts
    unsigned short* q2l = q2h + (size_t)B * D;

    // sub-allocations inside PART:
    int*   cand2 = (int*)(part + WSP_CAND);                   // 64*64
    float* rvals = part + WSP_RVAL;                           // 64*64
    int*   tidx  = (int*)(part + WSP_TIDX);                   // 64*50

    float* outv   = (float*)d_out;
    float* chitta = outv;                                   // [64][50][2048]
    float* attn   = outv + (size_t)B * KTOP * D;            // [64][50000]
    float* oidxf  = attn + (size_t)B * NSEED;               // [64][50] as float

    // MLP layer 1: 64 n-blocks x 8 k-chunks (kcK=256) -> 512 blocks, 2/CU
    gemm64p_kernel<<<64 * 8, 256, 0, stream>>>(query, W1, logits, D, H, 256, 64);
    mlp_reduce_kernel<<<(B * H) / 256, 256, 0, stream>>>(logits, b1, h, H, 8, 1, nullptr, nullptr);
    // MLP layer 2: 32 n-blocks x 8 k-chunks (kcK=512) -> 256 blocks; fused q2 split
    gemm64p_kernel<<<32 * 8, 256, 0, stream>>>(h, W2, logits, H, D, 512, 32);
    mlp_reduce_kernel<<<(B * D) / 256, 256, 0, stream>>>(logits, b2, q2, D, 8, 0, q2h, q2l);
    // similarity + gate + bias -> logits (drain-free barrier pipeline)
    sims_mfma_kernel<<<(NSEED + 63) / 64, 256, 0, stream>>>(q2h, q2l, seed, karma, types, vbias, logits);
    // per-chunk stats + top-20 candidates
    chunk_topk_kernel<<<B * NCHUNKS, 64, 0, stream>>>(logits, cm, cs, cval, cidx);
    // per-row merge -> (M, 1/S) + top-NCAND candidate set
    merge_topk_kernel<<<B, 256, 0, stream>>>(cm, cs, cval, cidx, rM, rS, cand2);
    // exact fp64 rescore of candidates
    rescore_kernel<<<dim3(NCAND / 4, B), 256, 0, stream>>>(q2, seed, karma, types, vbias, cand2, rvals);
    // final sorted top-50 indices
    final50_kernel<<<B, 64, 0, stream>>>(rvals, cand2, oidxf, tidx);
    // full attention weights
    weights_kernel<<<dim3((NSEED / 4 + 255) / 256, B), 256, 0, stream>>>(logits, rM, rS, attn);
    // retrieved embeddings
    gather_kernel<<<dim3(KTOP, B), 256, 0, stream>>>(seed, tidx, chitta);
}

// Round 11
// 318.099 us; speedup vs baseline: 1.5538x; 1.0076x over previous
//
#include <hip/hip_runtime.h>
#include <math.h>

// Problem constants
#define B 64
#define D 2048
#define H 4096
#define NSEED 50000
#define KTOP 50
#define NCAND 64            // rescored candidates per row
#define CEMIT 20            // candidates emitted per chunk (P(chunk holds >20 of top-64) ~ 2e-20)
#define NCHUNKS 64          // topk chunks per row
#define CHUNK_SZ 782        // ceil(50000/64)

// ws layout (float offsets)
#define WS_LOGITS   0                         // 64*50000 = 3,200,000 (also MLP partials)
#define WS_H        3200000                   // 64*4096  = 262,144
#define WS_Q2       (WS_H + B*H)              // 64*2048  = 131,072
#define WS_PART     (WS_Q2 + B*D)             // 1,048,576 (cand/rvals/tidx live here)
#define WS_CVAL     (WS_PART + 1048576)       // 64*64*20 = 81,920 (region sized 262,144)
#define WS_CIDX     (WS_CVAL + 262144)        // ints
#define WS_CM       (WS_CIDX + 262144)        // 4096
#define WS_CS       (WS_CM + 4096)            // 4096
#define WS_RM       (WS_CS + 4096)            // 64
#define WS_RS       (WS_RM + 64)              // 64
#define WS_Q2HL     (WS_RS + 64)              // q2h+q2l: 2*131072 ushorts = 131,072 floats
// sub-allocations inside the PART region:
#define WSP_CAND    200000                    // 64*64 ints
#define WSP_RVAL    220000                    // 64*64 floats
#define WSP_TIDX    240000                    // 64*50 ints

typedef short s16x8 __attribute__((ext_vector_type(8)));
typedef float f32x4 __attribute__((ext_vector_type(4)));

// ---------------------------------------------------------------------------
// bf16 split helpers (RNE, used on the q2 path)
// ---------------------------------------------------------------------------
__device__ __forceinline__ unsigned short bf16_rne(float x)
{
    unsigned int b = __float_as_uint(x);
    b += 0x7FFFu + ((b >> 16) & 1u);
    return (unsigned short)(b >> 16);
}
__device__ __forceinline__ float bf16_tof(unsigned short h)
{
    return __uint_as_float(((unsigned int)h) << 16);
}

// ---------------------------------------------------------------------------
// MLP GEMM, pipelined fp32 (kept fp32 deliberately — q2 accuracy gates the
// topk-index ordering). C_partial[kc][64][N] = A[64][Kc] @ W[Kc][N]
// (exact round-7 configuration — known-good)
// ---------------------------------------------------------------------------
__global__ __launch_bounds__(256) void gemm64p_kernel(
    const float* __restrict__ A, const float* __restrict__ W,
    float* __restrict__ part, int K, int N, int kcK, int nBlocks)
{
    __shared__ float As[2][32][68];   // [buf][k][m]
    __shared__ float Bs[2][32][68];   // [buf][k][n]

    const int tid = threadIdx.x;
    const int nb = blockIdx.x % nBlocks;
    const int kc = blockIdx.x / nBlocks;
    const int kbeg = kc * kcK;

    const int tidm = tid >> 4;          // 0..15
    const int tidn = tid & 15;          // 0..15
    const int m0 = tidm * 4;
    const int n0 = tidn * 4;

    const int ar0 = tid >> 3, ac0 = tid & 7;    // + second A float4 at row ar0+32
    const int wr0 = tid >> 4, wc0 = tid & 15;   // + second B float4 at k-row wr0+16

    const float* Aptr0 = A + (size_t)ar0 * K + kbeg + ac0 * 4;
    const float* Aptr1 = A + (size_t)(ar0 + 32) * K + kbeg + ac0 * 4;
    const float* Wptr0 = W + (size_t)(kbeg + wr0) * N + nb * 64 + wc0 * 4;
    const float* Wptr1 = W + (size_t)(kbeg + wr0 + 16) * N + nb * 64 + wc0 * 4;

    float acc[4][4];
#pragma unroll
    for (int i = 0; i < 4; ++i)
#pragma unroll
        for (int j = 0; j < 4; ++j) acc[i][j] = 0.f;

    float4 pa0 = *(const float4*)(Aptr0);
    float4 pa1 = *(const float4*)(Aptr1);
    float4 pb0 = *(const float4*)(Wptr0);
    float4 pb1 = *(const float4*)(Wptr1);

    const int nsteps = kcK / 32;
    for (int s = 0; s < nsteps; ++s) {
        const int buf = s & 1;
        As[buf][ac0 * 4 + 0][ar0] = pa0.x;
        As[buf][ac0 * 4 + 1][ar0] = pa0.y;
        As[buf][ac0 * 4 + 2][ar0] = pa0.z;
        As[buf][ac0 * 4 + 3][ar0] = pa0.w;
        As[buf][ac0 * 4 + 0][ar0 + 32] = pa1.x;
        As[buf][ac0 * 4 + 1][ar0 + 32] = pa1.y;
        As[buf][ac0 * 4 + 2][ar0 + 32] = pa1.z;
        As[buf][ac0 * 4 + 3][ar0 + 32] = pa1.w;
        *(float4*)&Bs[buf][wr0][wc0 * 4] = pb0;
        *(float4*)&Bs[buf][wr0 + 16][wc0 * 4] = pb1;
        if (s + 1 < nsteps) {
            const int ko = 32 * (s + 1);
            pa0 = *(const float4*)(Aptr0 + ko);
            pa1 = *(const float4*)(Aptr1 + ko);
            pb0 = *(const float4*)(Wptr0 + (size_t)ko * N);
            pb1 = *(const float4*)(Wptr1 + (size_t)ko * N);
        }
        __syncthreads();
#pragma unroll
        for (int kk = 0; kk < 32; ++kk) {
            float4 a = *(const float4*)&As[buf][kk][m0];
            float4 b = *(const float4*)&Bs[buf][kk][n0];
            float av[4] = {a.x, a.y, a.z, a.w};
            float bv[4] = {b.x, b.y, b.z, b.w};
#pragma unroll
            for (int i = 0; i < 4; ++i)
#pragma unroll
                for (int j = 0; j < 4; ++j)
                    acc[i][j] += av[i] * bv[j];
        }
    }

#pragma unroll
    for (int i = 0; i < 4; ++i) {
        float4 v;
        v.x = acc[i][0]; v.y = acc[i][1]; v.z = acc[i][2]; v.w = acc[i][3];
        *(float4*)(part + (size_t)(kc * B + m0 + i) * N + nb * 64 + n0) = v;
    }
}

// Reduce K-chunk partials + bias (+ optional exact GELU).
// When uh/ul are non-null (layer 2), also emits the bf16 hi/lo split of out.
__global__ void mlp_reduce_kernel(const float* __restrict__ part,
                                  const float* __restrict__ bias,
                                  float* __restrict__ out, int N, int nchunks, int gelu,
                                  unsigned short* __restrict__ uh,
                                  unsigned short* __restrict__ ul)
{
    int e = blockIdx.x * 256 + threadIdx.x;   // over B*N
    int b = e / N, j = e - b * N;
    float s = bias[j];
    for (int c = 0; c < nchunks; ++c)
        s += part[(size_t)(c * B + b) * N + j];
    if (gelu)
        s = 0.5f * s * (1.0f + erff(s * 0.70710678118654752f));
    out[e] = s;
    if (uh) {
        unsigned short h = bf16_rne(s);
        uh[e] = h;
        ul[e] = bf16_rne(s - bf16_tof(h));
    }
}

// int64-layout hedge for vritti_types (values 0..4 -> high words all zero)
__device__ __forceinline__ bool types_is_i64(const int* t)
{
    int acc = 0;
#pragma unroll
    for (int j = 0; j < 16; ++j) acc |= t[2 * j + 1];
    return acc == 0;
}

// ---------------------------------------------------------------------------
// sims via split-bf16 MFMA, K-step 64 — round-10 structure with three
// occupancy changes:
//  (1) single A register set (depth-1 A prefetch; A hits L2 ~250cyc, covered
//      by one phase) — saves 16 VGPR vs the 2-set design.
//  (2) truncation-split conversion (hi = chop-16; lo = chop(x-hi)): ~4.5
//      VALU/elem, pairs pack straight into u32. Error ~2^-16|a||b| per term
//      -> logit sigma ~2e-5, absorbed by the exact-rescore candidate margin.
//  (3) __launch_bounds__(256,4): cap VGPR at 128 -> 4 waves/SIMD ->
//      4 blocks/CU (LDS 147KB/160KB) -> all 782 blocks co-resident, +33%
//      in-flight loads, no scheduling tail.
// B (seed, HBM, read-once) keeps the depth-2 register pipeline; barriers are
// raw s_barrier + lgkmcnt(0) (no vmcnt drain), proven r10.
// ---------------------------------------------------------------------------
__global__ __launch_bounds__(256, 4) void sims_mfma_kernel(
    const unsigned short* __restrict__ q2h, const unsigned short* __restrict__ q2l,
    const float* __restrict__ seed,
    const float* __restrict__ karma, const int* __restrict__ types,
    const float* __restrict__ vbias, float* __restrict__ logits)
{
    __shared__ __align__(16) unsigned short Ash[2][64][72];
    __shared__ __align__(16) unsigned short Asl[2][64][72];

    const int tid = threadIdx.x;
    const int n0 = blockIdx.x * 64;
    const int lane = tid & 63;
    const int wv  = tid >> 6;       // 0..3: n-tile of this wave
    const int l15 = lane & 15;
    const int lg  = lane >> 4;      // k-group 0..3

    const int srow = tid >> 2;      // A staging row 0..63
    const int seg  = tid & 3;       // A staging 16-short segment

    const int nrow = n0 + wv * 16 + l15;            // seed row this lane owns
    const bool nvalid = nrow < NSEED;
    const float* brow = seed + (size_t)nrow * D + 8 * lg;
    const size_t aoff = (size_t)srow * D + 16 * seg;

    f32x4 acc[4];
#pragma unroll
    for (int t = 0; t < 4; ++t) acc[t] = (f32x4){0.f, 0.f, 0.f, 0.f};

    // -------- pipeline registers --------
    s16x8 aha, ahb, ala, alb;       // SINGLE A set (depth-1)
    float4 b00, b01, b02, b03;      // B set 0 (even phases): k +[0,4,32,36]
    float4 b10, b11, b12, b13;      // B set 1 (odd phases)

    // prologue: A(phase 0), B(phase 0), B(phase 1)
    aha = *(const s16x8*)(q2h + aoff);
    ahb = *(const s16x8*)(q2h + aoff + 8);
    ala = *(const s16x8*)(q2l + aoff);
    alb = *(const s16x8*)(q2l + aoff + 8);
    b00 = b01 = b02 = b03 = make_float4(0.f, 0.f, 0.f, 0.f);
    b10 = b11 = b12 = b13 = make_float4(0.f, 0.f, 0.f, 0.f);
    if (nvalid) {
        b00 = *(const float4*)(brow);      b01 = *(const float4*)(brow + 4);
        b02 = *(const float4*)(brow + 32); b03 = *(const float4*)(brow + 36);
        b10 = *(const float4*)(brow + 64); b11 = *(const float4*)(brow + 68);
        b12 = *(const float4*)(brow + 96); b13 = *(const float4*)(brow + 100);
    }

    // drain-free barrier: ds_writes done (lgkmcnt), then s_barrier; no vmcnt.
#define SIMS_BARRIER() asm volatile("s_waitcnt lgkmcnt(0)\n\ts_barrier" ::: "memory")

    // truncation split: hi = chop-16(x); lo = chop-16(x - hi). Pair-packed.
#define SIMS_CONV(F0, F1, BH, BL)                                          \
    {                                                                      \
        union { unsigned int w[4]; s16x8 v; } uh_, ul_;                    \
        float xs[8] = {F0.x, F0.y, F0.z, F0.w, F1.x, F1.y, F1.z, F1.w};    \
        _Pragma("unroll")                                                  \
        for (int j = 0; j < 4; ++j) {                                      \
            unsigned int u0 = __float_as_uint(xs[2 * j]);                  \
            unsigned int u1 = __float_as_uint(xs[2 * j + 1]);              \
            unsigned int h0 = u0 & 0xFFFF0000u;                            \
            unsigned int h1 = u1 & 0xFFFF0000u;                            \
            uh_.w[j] = (u0 >> 16) | h1;                                    \
            float r0 = xs[2 * j]     - __uint_as_float(h0);                \
            float r1 = xs[2 * j + 1] - __uint_as_float(h1);                \
            ul_.w[j] = (__float_as_uint(r0) >> 16)                         \
                     | (__float_as_uint(r1) & 0xFFFF0000u);                \
        }                                                                  \
        BH = uh_.v; BL = ul_.v;                                            \
    }

#define SIMS_MFMA(BUF, KS, BH, BL)                                         \
    _Pragma("unroll")                                                      \
    for (int t = 0; t < 4; ++t) {                                          \
        s16x8 ah = *(const s16x8*)&Ash[BUF][t * 16 + l15][KS * 32 + 8 * lg]; \
        s16x8 al = *(const s16x8*)&Asl[BUF][t * 16 + l15][KS * 32 + 8 * lg]; \
        acc[t] = __builtin_amdgcn_mfma_f32_16x16x32_bf16(ah, BH, acc[t], 0, 0, 0); \
        acc[t] = __builtin_amdgcn_mfma_f32_16x16x32_bf16(al, BH, acc[t], 0, 0, 0); \
        acc[t] = __builtin_amdgcn_mfma_f32_16x16x32_bf16(ah, BL, acc[t], 0, 0, 0); \
    }

    for (int u = 0; u < 16; ++u) {
        // ============ phase 2u (buffer 0, B set 0) ============
        *(s16x8*)&Ash[0][srow][16 * seg]     = aha;
        *(s16x8*)&Ash[0][srow][16 * seg + 8] = ahb;
        *(s16x8*)&Asl[0][srow][16 * seg]     = ala;
        *(s16x8*)&Asl[0][srow][16 * seg + 8] = alb;
        {   // A for phase 2u+1 (always in range: kb <= 1984)
            const int kb = 128 * u + 64;
            aha = *(const s16x8*)(q2h + aoff + kb);
            ahb = *(const s16x8*)(q2h + aoff + kb + 8);
            ala = *(const s16x8*)(q2l + aoff + kb);
            alb = *(const s16x8*)(q2l + aoff + kb + 8);
        }
        float4 n0a = make_float4(0.f, 0.f, 0.f, 0.f), n0b = n0a, n0c = n0a, n0d = n0a;
        if (u < 15 && nvalid) {                    // B for phase 2u+2
            const int kb = 128 * u + 128;
            n0a = *(const float4*)(brow + kb);      n0b = *(const float4*)(brow + kb + 4);
            n0c = *(const float4*)(brow + kb + 32); n0d = *(const float4*)(brow + kb + 36);
        }
        SIMS_BARRIER();
        {
            s16x8 bh, bl;
            SIMS_CONV(b00, b01, bh, bl);
            SIMS_MFMA(0, 0, bh, bl);
            SIMS_CONV(b02, b03, bh, bl);
            SIMS_MFMA(0, 1, bh, bl);
        }
        b00 = n0a; b01 = n0b; b02 = n0c; b03 = n0d;

        // ============ phase 2u+1 (buffer 1, B set 1) ============
        *(s16x8*)&Ash[1][srow][16 * seg]     = aha;
        *(s16x8*)&Ash[1][srow][16 * seg + 8] = ahb;
        *(s16x8*)&Asl[1][srow][16 * seg]     = ala;
        *(s16x8*)&Asl[1][srow][16 * seg + 8] = alb;
        if (u < 15) {                              // A for phase 2u+2
            const int kb = 128 * u + 128;
            aha = *(const s16x8*)(q2h + aoff + kb);
            ahb = *(const s16x8*)(q2h + aoff + kb + 8);
            ala = *(const s16x8*)(q2l + aoff + kb);
            alb = *(const s16x8*)(q2l + aoff + kb + 8);
        }
        float4 n1a = make_float4(0.f, 0.f, 0.f, 0.f), n1b = n1a, n1c = n1a, n1d = n1a;
        if (u < 15 && nvalid) {                    // B for phase 2u+3
            const int kb = 128 * u + 192;
            n1a = *(const float4*)(brow + kb);      n1b = *(const float4*)(brow + kb + 4);
            n1c = *(const float4*)(brow + kb + 32); n1d = *(const float4*)(brow + kb + 36);
        }
        SIMS_BARRIER();
        {
            s16x8 bh, bl;
            SIMS_CONV(b10, b11, bh, bl);
            SIMS_MFMA(1, 0, bh, bl);
            SIMS_CONV(b12, b13, bh, bl);
            SIMS_MFMA(1, 1, bh, bl);
        }
        b10 = n1a; b11 = n1b; b12 = n1c; b13 = n1d;
    }
#undef SIMS_CONV
#undef SIMS_MFMA
#undef SIMS_BARRIER

    // epilogue: gate + vritti bias. D layout: col=lane&15, row=4*lg+reg.
    if (nvalid) {
        const bool i64 = types_is_i64(types);
        float ka = karma[nrow];
        float gate = 1.0f / (1.0f + expf(-(ka + 0.3f) * 10.0f));
        int ty = i64 ? types[2 * nrow] : types[nrow];
        float bias = vbias[ty];
#pragma unroll
        for (int t = 0; t < 4; ++t) {
#pragma unroll
            for (int r = 0; r < 4; ++r) {
                int m = t * 16 + lg * 4 + r;
                logits[(size_t)m * NSEED + nrow] = acc[t][r] * gate + bias;
            }
        }
    }
}

// ---------------------------------------------------------------------------
// Per-(row,chunk): online softmax partial (m,s) + chunk top-CEMIT.
// grid = 64 rows * 64 chunks, 64 threads (1 wave).
// ---------------------------------------------------------------------------
__global__ __launch_bounds__(64) void chunk_topk_kernel(
    const float* __restrict__ logits,
    float* __restrict__ chunk_m, float* __restrict__ chunk_s,
    float* __restrict__ cand_val, int* __restrict__ cand_idx)
{
    const int bid = blockIdx.x;
    const int row = bid >> 6, chunk = bid & 63;
    const int start = chunk * CHUNK_SZ;
    const int end = min(start + CHUNK_SZ, NSEED);
    const int lane = threadIdx.x;
    const float* Lrow = logits + (size_t)row * NSEED;

    float v[13];
#pragma unroll
    for (int j = 0; j < 13; ++j) {
        int e = start + lane + j * 64;
        v[j] = (e < end) ? Lrow[e] : -INFINITY;
    }

    // online (m, s) partial: s = sum exp(2*(l - m))
    float m = v[0];
#pragma unroll
    for (int j = 1; j < 13; ++j) m = fmaxf(m, v[j]);
    float s = 0.f;
#pragma unroll
    for (int j = 0; j < 13; ++j) s += expf(2.f * (v[j] - m));
#pragma unroll
    for (int d = 1; d < 64; d <<= 1) {
        float mo = __shfl_xor(m, d);
        float so = __shfl_xor(s, d);
        float nm = fmaxf(m, mo);
        s = s * expf(2.f * (m - nm)) + so * expf(2.f * (mo - nm));
        m = nm;
    }
    if (lane == 0) { chunk_m[bid] = m; chunk_s[bid] = s; }

    // chunk top-CEMIT via wave-argmax iterations (lower index wins ties)
    for (int it = 0; it < CEMIT; ++it) {
        float bv = v[0]; int bj = 0;
#pragma unroll
        for (int j = 1; j < 13; ++j)
            if (v[j] > bv) { bv = v[j]; bj = j; }
        int bi = start + lane + bj * 64;
#pragma unroll
        for (int d = 1; d < 64; d <<= 1) {
            float ov = __shfl_xor(bv, d);
            int oi = __shfl_xor(bi, d);
            if (ov > bv || (ov == bv && oi < bi)) { bv = ov; bi = oi; }
        }
        if (lane == 0) {
            cand_val[bid * CEMIT + it] = bv;
            cand_idx[bid * CEMIT + it] = bi;
        }
#pragma unroll
        for (int j = 0; j < 13; ++j)
            if (start + lane + j * 64 == bi) v[j] = -INFINITY;
    }
}

// ---------------------------------------------------------------------------
// Per-row merge: 64 (m,s) partials -> (M, 1/S); 1280 candidates -> top-NCAND
// candidate indices (by MFMA logit; candidate set, not final order).
// ---------------------------------------------------------------------------
__global__ __launch_bounds__(256) void merge_topk_kernel(
    const float* __restrict__ chunk_m, const float* __restrict__ chunk_s,
    const float* __restrict__ cand_val, const int* __restrict__ cand_idx,
    float* __restrict__ row_M, float* __restrict__ row_rS,
    int* __restrict__ cand2)
{
    const int row = blockIdx.x;
    const int tid = threadIdx.x;
    const int lane = tid & 63, wave = tid >> 6;
    __shared__ float rv[4];
    __shared__ int ri[4];

    if (wave == 0) {
        float m = chunk_m[row * 64 + lane];
        float s = chunk_s[row * 64 + lane];
#pragma unroll
        for (int d = 1; d < 64; d <<= 1) {
            float mo = __shfl_xor(m, d);
            float so = __shfl_xor(s, d);
            float nm = fmaxf(m, mo);
            s = s * expf(2.f * (m - nm)) + so * expf(2.f * (mo - nm));
            m = nm;
        }
        if (lane == 0) { row_M[row] = m; row_rS[row] = 1.0f / s; }
    }

    float v[5]; int ix[5];
#pragma unroll
    for (int j = 0; j < 5; ++j) {
        int e = tid + j * 256;                      // 1280 = NCHUNKS*CEMIT
        v[j] = cand_val[row * (NCHUNKS * CEMIT) + e];
        ix[j] = cand_idx[row * (NCHUNKS * CEMIT) + e];
    }

    for (int it = 0; it < NCAND; ++it) {
        float bv = v[0]; int bi = ix[0];
#pragma unroll
        for (int j = 1; j < 5; ++j)
            if (v[j] > bv || (v[j] == bv && ix[j] < bi)) { bv = v[j]; bi = ix[j]; }
#pragma unroll
        for (int d = 1; d < 64; d <<= 1) {
            float ov = __shfl_xor(bv, d);
            int oi = __shfl_xor(bi, d);
            if (ov > bv || (ov == bv && oi < bi)) { bv = ov; bi = oi; }
        }
        if (lane == 0) { rv[wave] = bv; ri[wave] = bi; }
        __syncthreads();
        float wv = rv[0]; int wi = ri[0];
#pragma unroll
        for (int w = 1; w < 4; ++w)
            if (rv[w] > wv || (rv[w] == wv && ri[w] < wi)) { wv = rv[w]; wi = ri[w]; }
        __syncthreads();
        if (tid == 0) cand2[row * NCAND + it] = wi;
#pragma unroll
        for (int j = 0; j < 5; ++j)
            if (ix[j] == wi) v[j] = -INFINITY;
    }
}

// ---------------------------------------------------------------------------
// Exact rescore of candidates: fp64 dot(q2[row], seed[idx]) + fp32 gate/bias.
// grid = (NCAND/4, 64 rows), 256 threads = 4 waves (one candidate per wave).
// ---------------------------------------------------------------------------
__global__ __launch_bounds__(256) void rescore_kernel(
    const float* __restrict__ q2, const float* __restrict__ seed,
    const float* __restrict__ karma, const int* __restrict__ types,
    const float* __restrict__ vbias, const int* __restrict__ cand2,
    float* __restrict__ rvals)
{
    const int row = blockIdx.y;
    const int wv = threadIdx.x >> 6, lane = threadIdx.x & 63;
    const int ci = blockIdx.x * 4 + wv;             // 0..NCAND-1
    const int idx = cand2[row * NCAND + ci];
    const float* qrow = q2 + (size_t)row * D;
    const float* srow = seed + (size_t)idx * D;

    double s = 0.0;
#pragma unroll
    for (int i = 0; i < 8; ++i) {
        float4 a = *(const float4*)(qrow + lane * 4 + i * 256);
        float4 b = *(const float4*)(srow + lane * 4 + i * 256);
        s += (double)a.x * (double)b.x + (double)a.y * (double)b.y
           + (double)a.z * (double)b.z + (double)a.w * (double)b.w;
    }
#pragma unroll
    for (int d = 1; d < 64; d <<= 1) s += __shfl_xor(s, d);

    if (lane == 0) {
        float ka = karma[idx];
        float gate = 1.0f / (1.0f + expf(-(ka + 0.3f) * 10.0f));
        bool i64 = types_is_i64(types);
        int ty = i64 ? types[2 * idx] : types[idx];
        rvals[row * NCAND + ci] = (float)s * gate + vbias[ty];
    }
}

// ---------------------------------------------------------------------------
// Final per-row top-50 (sorted desc, lower index on ties) from NCAND rescored.
// grid = 64, 64 threads (1 wave, one candidate per lane).
// ---------------------------------------------------------------------------
__global__ __launch_bounds__(64) void final50_kernel(
    const float* __restrict__ rvals, const int* __restrict__ cand2,
    float* __restrict__ out_idx_f, int* __restrict__ topk_idx)
{
    const int row = blockIdx.x;
    const int lane = threadIdx.x;

    float v = rvals[row * NCAND + lane];
    int ix = cand2[row * NCAND + lane];

    for (int it = 0; it < KTOP; ++it) {
        float bv = v; int bi = ix;
#pragma unroll
        for (int d = 1; d < 64; d <<= 1) {
            float ov = __shfl_xor(bv, d);
            int oi = __shfl_xor(bi, d);
            if (ov > bv || (ov == bv && oi < bi)) { bv = ov; bi = oi; }
        }
        if (lane == 0) {
            out_idx_f[row * KTOP + it] = (float)bi;
            topk_idx[row * KTOP + it] = bi;
        }
        if (ix == bi) v = -INFINITY;
    }
}

// attention weights: w = exp(2*(l - M)) / S
__global__ void weights_kernel(const float* __restrict__ logits,
                               const float* __restrict__ row_M,
                               const float* __restrict__ row_rS,
                               float* __restrict__ attn)
{
    const int row = blockIdx.y;
    const int f = blockIdx.x * 256 + threadIdx.x;
    if (f >= NSEED / 4) return;
    const float M = row_M[row], rS = row_rS[row];
    float4 l = ((const float4*)(logits + (size_t)row * NSEED))[f];
    float4 w;
    w.x = expf(2.f * (l.x - M)) * rS;
    w.y = expf(2.f * (l.y - M)) * rS;
    w.z = expf(2.f * (l.z - M)) * rS;
    w.w = expf(2.f * (l.w - M)) * rS;
    ((float4*)(attn + (size_t)row * NSEED))[f] = w;
}

// chitta gather: 2048 floats per (row,k)
__global__ void gather_kernel(const float* __restrict__ seed,
                              const int* __restrict__ topk_idx,
                              float* __restrict__ chitta)
{
    const int k = blockIdx.x, row = blockIdx.y;
    const int idx = topk_idx[row * KTOP + k];
    const float4* src = (const float4*)(seed + (size_t)idx * D);
    float4* dst = (float4*)(chitta + (size_t)(row * KTOP + k) * D);
#pragma unroll
    for (int j = 0; j < 2; ++j)
        dst[threadIdx.x + j * 256] = src[threadIdx.x + j * 256];
}

extern "C" void kernel_launch(void* const* d_in, const int* in_sizes, int n_in,
                              void* d_out, int out_size, void* d_ws, size_t ws_size,
                              hipStream_t stream)
{
    const float* query = (const float*)d_in[0];
    const int*   types = (const int*)d_in[1];
    const float* seed  = (const float*)d_in[2];
    const float* karma = (const float*)d_in[3];
    const float* vbias = (const float*)d_in[4];
    const float* W1    = (const float*)d_in[5];
    const float* b1    = (const float*)d_in[6];
    const float* W2    = (const float*)d_in[7];
    const float* b2    = (const float*)d_in[8];

    float* ws = (float*)d_ws;
    float* logits = ws + WS_LOGITS;   // also MLP partial buffer (freed before sims)
    float* h      = ws + WS_H;
    float* q2     = ws + WS_Q2;
    float* part   = ws + WS_PART;
    float* cval   = ws + WS_CVAL;
    int*   cidx   = (int*)(ws + WS_CIDX);
    float* cm     = ws + WS_CM;
    float* cs     = ws + WS_CS;
    float* rM     = ws + WS_RM;
    float* rS     = ws + WS_RS;

    // q2 bf16 hi/lo live in their own region (written by fused mlp_reduce L2)
    unsigned short* q2h = (unsigned short*)(ws + WS_Q2HL);   // 64*2048 ushorts
    unsigned short* q2l = q2h + (size_t)B * D;

    // sub-allocations inside PART:
    int*   cand2 = (int*)(part + WSP_CAND);                   // 64*64
    float* rvals = part + WSP_RVAL;                           // 64*64
    int*   tidx  = (int*)(part + WSP_TIDX);                   // 64*50

    float* outv   = (float*)d_out;
    float* chitta = outv;                                   // [64][50][2048]
    float* attn   = outv + (size_t)B * KTOP * D;            // [64][50000]
    float* oidxf  = attn + (size_t)B * NSEED;               // [64][50] as float

    // MLP layer 1: 64 n-blocks x 8 k-chunks (kcK=256) -> 512 blocks, 2/CU
    gemm64p_kernel<<<64 * 8, 256, 0, stream>>>(query, W1, logits, D, H, 256, 64);
    mlp_reduce_kernel<<<(B * H) / 256, 256, 0, stream>>>(logits, b1, h, H, 8, 1, nullptr, nullptr);
    // MLP layer 2: 32 n-blocks x 8 k-chunks (kcK=512) -> 256 blocks; fused q2 split
    gemm64p_kernel<<<32 * 8, 256, 0, stream>>>(h, W2, logits, H, D, 512, 32);
    mlp_reduce_kernel<<<(B * D) / 256, 256, 0, stream>>>(logits, b2, q2, D, 8, 0, q2h, q2l);
    // similarity + gate + bias -> logits (128-VGPR, 4 blocks/CU pipeline)
    sims_mfma_kernel<<<(NSEED + 63) / 64, 256, 0, stream>>>(q2h, q2l, seed, karma, types, vbias, logits);
    // per-chunk stats + top-20 candidates
    chunk_topk_kernel<<<B * NCHUNKS, 64, 0, stream>>>(logits, cm, cs, cval, cidx);
    // per-row merge -> (M, 1/S) + top-NCAND candidate set
    merge_topk_kernel<<<B, 256, 0, stream>>>(cm, cs, cval, cidx, rM, rS, cand2);
    // exact fp64 rescore of candidates
    rescore_kernel<<<dim3(NCAND / 4, B), 256, 0, stream>>>(q2, seed, karma, types, vbias, cand2, rvals);
    // final sorted top-50 indices
    final50_kernel<<<B, 64, 0, stream>>>(rvals, cand2, oidxf, tidx);
    // full attention weights
    weights_kernel<<<dim3((NSEED / 4 + 255) / 256, B), 256, 0, stream>>>(logits, rM, rS, attn);
    // retrieved embeddings
    gather_kernel<<<dim3(KTOP, B), 256, 0, stream>>>(seed, tidx, chitta);
}